// Round 6
// baseline (28644.226 us; speedup 1.0000x reference)
//
#include <hip/hip_runtime.h>
#include <hip/hip_fp16.h>

// SpellerModel round 6: ONE persistent cooperative kernel, 256 WGs x 512 thr.
// Coherence rule: ALL cross-WG data moves via atomic RMW (exchange for
// stores, inline-asm atomic-or-0 w/ sc0 sc1 for loads) -> executes at the
// coherent point, no fences, no cache invalidates, L2 stays weight-hot.
// fp16 X buffers + fp16 weights, v_dot2_f32_f16 GEMMs, fp32 c-state in regs.

#define BB 64
#define TT 200
#define SS 400
#define VV 34
#define EE 256
#define HH 512
#define KD 256
#define NSTEP 201
#define NWG 256
#define TPB 512

typedef unsigned long long u64;

// ---- workspace byte offsets ----
#define OX1   0u            // halves [2][64][1024] (emb|ctx|h1)
#define OX2   262144u       // halves [2][64][1024] (h1|h2)
#define OX3   524288u       // halves [2][64][1024] (h2|h3)
#define OBS1  786432u       // f32 [2048] bih+bhh
#define OBS2  794624u
#define OBS3  802816u
#define OWVT  811008u       // f32 [512][34]
#define OLACC 880640u       // f32 [64]
#define OBAR  880896u       // u32 [512]
#define OW16  1048576u      // fp16 [3][2048][1024] (Wih|Whh per row)
#define OWQ   13631488u     // fp16 [256][512]
#define OKEY  13893632u     // fp16 [64][400][256]
#define OVAL  27000832u     // fp16 [64][400][256]

// ---------------- coherent-point RMW helpers ------------------------------
__device__ __forceinline__ unsigned aload_u32(const unsigned* p) {
  unsigned v;
  asm volatile(
      "global_atomic_or %0, %1, %2, off sc0 sc1\n\t"
      "s_waitcnt vmcnt(0)"
      : "=&v"(v)
      : "v"(p), "v"(0u)
      : "memory");
  return v;
}
__device__ __forceinline__ u64 aload_u64(const u64* p) {
  u64 v;
  asm volatile(
      "global_atomic_or_x2 %0, %1, %2, off sc0 sc1\n\t"
      "s_waitcnt vmcnt(0)"
      : "=&v"(v)
      : "v"(p), "v"(0ull)
      : "memory");
  return v;
}
__device__ __forceinline__ void aload4_u64(const u64* p0, const u64* p1,
                                           const u64* p2, const u64* p3,
                                           u64& r0, u64& r1, u64& r2,
                                           u64& r3) {
  asm volatile(
      "global_atomic_or_x2 %0, %4, %8, off sc0 sc1\n\t"
      "global_atomic_or_x2 %1, %5, %8, off sc0 sc1\n\t"
      "global_atomic_or_x2 %2, %6, %8, off sc0 sc1\n\t"
      "global_atomic_or_x2 %3, %7, %8, off sc0 sc1\n\t"
      "s_waitcnt vmcnt(0)"
      : "=&v"(r0), "=&v"(r1), "=&v"(r2), "=&v"(r3)
      : "v"(p0), "v"(p1), "v"(p2), "v"(p3), "v"(0ull)
      : "memory");
}
__device__ __forceinline__ void astore_u32(unsigned* p, unsigned v) {
  __hip_atomic_exchange(p, v, __ATOMIC_RELAXED, __HIP_MEMORY_SCOPE_AGENT);
}
__device__ __forceinline__ void astore_u64(u64* p, u64 v) {
  __hip_atomic_exchange(p, v, __ATOMIC_RELAXED, __HIP_MEMORY_SCOPE_AGENT);
}

// ---------------- fp16 pack / dot helpers ---------------------------------
__device__ __forceinline__ unsigned pack2h(float a, float b) {
  return (unsigned)__half_as_ushort(__float2half(a)) |
         ((unsigned)__half_as_ushort(__float2half(b)) << 16);
}
__device__ __forceinline__ u64 pack4h(float4 v) {
  return (u64)pack2h(v.x, v.y) | ((u64)pack2h(v.z, v.w) << 32);
}
__device__ __forceinline__ float dot2acc(unsigned x, unsigned w, float acc) {
#if __has_builtin(__builtin_amdgcn_fdot2)
  typedef _Float16 h2 __attribute__((ext_vector_type(2)));
  union C { unsigned u; h2 h; };
  C a, b;
  a.u = x;
  b.u = w;
  return __builtin_amdgcn_fdot2(a.h, b.h, acc, false);
#else
  const __half2 ha = *(const __half2*)&x, hb = *(const __half2*)&w;
  const float2 fa = __half22float2(ha), fb = __half22float2(hb);
  return fmaf(fa.y, fb.y, fmaf(fa.x, fb.x, acc));
#endif
}

// ---------------------------- LDS union -----------------------------------
struct __align__(16) SM {
  union {
    struct { unsigned x[4096]; float gates[512]; } l;    // 18.4 KB lstm
    struct {
      unsigned h3u[256];
      float qp[2][256];
      float qf[256];
      unsigned qh[128];
      float an[SS];
      float red[8];
      float cxp[2][256];
    } a;                                                  // 8.3 KB attn
    struct { float h3f[512]; float redl[VV * 8]; float lbuf[VV]; } g;
  };
};

// ------------------------- fence-free global barrier ----------------------
__device__ __forceinline__ void gbar(unsigned* bar, int wg) {
  __syncthreads();
  if (threadIdx.x == 0) {
    unsigned* cnt = bar + (wg >> 5) * 16;
    unsigned* gen = bar + 128 + (wg >> 5) * 16;
    unsigned* rc = bar + 256;
    unsigned* rgen = bar + 272;
    const unsigned g0 = aload_u32(gen);
    if (__hip_atomic_fetch_add(cnt, 1u, __ATOMIC_RELAXED,
                               __HIP_MEMORY_SCOPE_AGENT) == 31u) {
      const unsigned r0 = aload_u32(rgen);
      if (__hip_atomic_fetch_add(rc, 1u, __ATOMIC_RELAXED,
                                 __HIP_MEMORY_SCOPE_AGENT) == 7u) {
        __hip_atomic_fetch_add(rc, (unsigned)-8, __ATOMIC_RELAXED,
                               __HIP_MEMORY_SCOPE_AGENT);
        __hip_atomic_fetch_add(rgen, 1u, __ATOMIC_RELAXED,
                               __HIP_MEMORY_SCOPE_AGENT);
      } else {
        while (aload_u32(rgen) == r0) __builtin_amdgcn_s_sleep(1);
      }
      __hip_atomic_fetch_add(cnt, (unsigned)-32, __ATOMIC_RELAXED,
                             __HIP_MEMORY_SCOPE_AGENT);
      __hip_atomic_fetch_add(gen, 1u, __ATOMIC_RELAXED,
                             __HIP_MEMORY_SCOPE_AGENT);
    } else {
      while (aload_u32(gen) == g0) __builtin_amdgcn_s_sleep(1);
    }
    asm volatile("" ::: "memory");
  }
  __syncthreads();
}

// ------------------------------- LSTM stage -------------------------------
// WG: cgI = wg&31 (16 units -> 64 gate rows), b0 = (wg>>5)*8 (8 batches).
// wave = batch, lane = gate row; x broadcast from LDS, W16 from L2, dot2.
__device__ __forceinline__ void lstm_stage(SM& sm, int cgI, int b0,
                                           const u64* Xc,
                                           const unsigned short* W16,
                                           const float* __restrict__ bsum,
                                           float& creg, unsigned* d1, int o1,
                                           unsigned* d2, int o2) {
  const int tid = threadIdx.x;
  {  // stage x[b0..b0+8][0:1024] halves via RMW (2048 u64, 4/thread)
    const u64* src = Xc + (size_t)b0 * 256;
    u64 r0, r1, r2, r3;
    aload4_u64(src + tid, src + tid + 512, src + tid + 1024, src + tid + 1536,
               r0, r1, r2, r3);
    *(u64*)&sm.l.x[(size_t)tid * 2] = r0;
    *(u64*)&sm.l.x[(size_t)(tid + 512) * 2] = r1;
    *(u64*)&sm.l.x[(size_t)(tid + 1024) * 2] = r2;
    *(u64*)&sm.l.x[(size_t)(tid + 1536) * 2] = r3;
  }
  __syncthreads();
  {
    const int bl = tid >> 6, r = tid & 63;
    const int R = ((r >> 4) << 9) + (cgI << 4) + (r & 15);
    const unsigned* wrow = (const unsigned*)W16 + (size_t)R * 512;
    const unsigned* xrow = &sm.l.x[bl * 512];
    float acc = 0.f;
#pragma unroll 8
    for (int kk = 0; kk < 128; ++kk) {
      const uint4 w4 = *(const uint4*)&wrow[kk * 4];
      const uint4 x4 = *(const uint4*)&xrow[kk * 4];
      acc = dot2acc(x4.x, w4.x, acc);
      acc = dot2acc(x4.y, w4.y, acc);
      acc = dot2acc(x4.z, w4.z, acc);
      acc = dot2acc(x4.w, w4.w, acc);
    }
    sm.l.gates[bl * 64 + r] = acc;
  }
  __syncthreads();
  if (tid < 128) {
    const int bl = tid >> 4, uu = tid & 15;
    const int u = (cgI << 4) + uu;
    const float* g = &sm.l.gates[bl * 64];
    const float gi = g[uu] + bsum[u];
    const float gf = g[16 + uu] + bsum[512 + u];
    const float gG = g[32 + uu] + bsum[1024 + u];
    const float go = g[48 + uu] + bsum[1536 + u];
    const float si = 1.f / (1.f + expf(-gi));
    const float sf = 1.f / (1.f + expf(-gf));
    const float so = 1.f / (1.f + expf(-go));
    const float cn = sf * creg + si * tanhf(gG);
    const float hn = so * tanhf(cn);
    creg = cn;
    const unsigned hb = (unsigned)__half_as_ushort(__float2half(hn));
    const unsigned ob = __shfl_down(hb, 1);
    if ((uu & 1) == 0) {
      const unsigned pk = hb | (ob << 16);
      const size_t off = (size_t)(b0 + bl) * 512 + (u >> 1);
      astore_u32(d1 + off + o1, pk);
      if (d2) astore_u32(d2 + off + o2, pk);
    }
  }
  __syncthreads();
}

// --------------------- attention (incl. its own q) ------------------------
__device__ __forceinline__ void attn_stage(
    SM& sm, int b, int t, const u64* X3n, const unsigned short* Wq16,
    const float* __restrict__ bq, const __half* __restrict__ key16,
    const __half* __restrict__ val16, const float* __restrict__ amask,
    unsigned* X1n32, float* __restrict__ dout) {
  const int tid = threadIdx.x;
  if (tid < 128) {
    const u64 v = aload_u64(X3n + (size_t)b * 256 + 128 + tid);
    *(u64*)&sm.a.h3u[(size_t)tid * 2] = v;
  }
  __syncthreads();
  {  // q = h3 @ Wq.T (fp16 dot2, c x k-half over 512 thr)
    const int c = tid & 255, kh = tid >> 8;
    const unsigned* wq = (const unsigned*)Wq16 + (size_t)c * 256 + kh * 128;
    const unsigned* hp = &sm.a.h3u[kh * 128];
    float a = 0.f;
#pragma unroll 8
    for (int i = 0; i < 32; ++i) {
      const uint4 w4 = *(const uint4*)&wq[i * 4];
      const uint4 x4 = *(const uint4*)&hp[i * 4];
      a = dot2acc(x4.x, w4.x, a);
      a = dot2acc(x4.y, w4.y, a);
      a = dot2acc(x4.z, w4.z, a);
      a = dot2acc(x4.w, w4.w, a);
    }
    sm.a.qp[kh][c] = a;
  }
  __syncthreads();
  if (tid < 256) sm.a.qf[tid] = sm.a.qp[0][tid] + sm.a.qp[1][tid] + bq[tid];
  __syncthreads();
  if (tid < 128) sm.a.qh[tid] = pack2h(sm.a.qf[2 * tid], sm.a.qf[2 * tid + 1]);
  __syncthreads();
  // energy
  float e = -1e30f;
  if (tid < SS) {
    const unsigned* kp = (const unsigned*)key16 + ((size_t)b * SS + tid) * 128;
    float a = 0.f;
#pragma unroll 8
    for (int i = 0; i < 32; ++i) {
      const uint4 k4 = *(const uint4*)&kp[i * 4];
      const uint4 q4 = *(const uint4*)&sm.a.qh[i * 4];
      a = dot2acc(q4.x, k4.x, a);
      a = dot2acc(q4.y, k4.y, a);
      a = dot2acc(q4.z, k4.z, a);
      a = dot2acc(q4.w, k4.w, a);
    }
    e = a;
  }
  // softmax
  float m = e;
  for (int o = 32; o; o >>= 1) m = fmaxf(m, __shfl_xor(m, o));
  if ((tid & 63) == 0) sm.a.red[tid >> 6] = m;
  __syncthreads();
  m = sm.a.red[0];
#pragma unroll
  for (int i = 1; i < 8; ++i) m = fmaxf(m, sm.a.red[i]);
  __syncthreads();
  const float p = (tid < SS) ? expf(e - m) : 0.f;
  float z = p;
  for (int o = 32; o; o >>= 1) z += __shfl_xor(z, o);
  if ((tid & 63) == 0) sm.a.red[tid >> 6] = z;
  __syncthreads();
  z = 0.f;
#pragma unroll
  for (int i = 0; i < 8; ++i) z += sm.a.red[i];
  __syncthreads();
  const float at = p / z;
  if (b == 0 && tid < SS) dout[1 + (size_t)t * SS + tid] = at;
  // masked renormalize
  const float am = (tid < SS) ? at * amask[(size_t)b * SS + tid] : 0.f;
  float sa = fabsf(am);
  for (int o = 32; o; o >>= 1) sa += __shfl_xor(sa, o);
  if ((tid & 63) == 0) sm.a.red[tid >> 6] = sa;
  __syncthreads();
  sa = 0.f;
#pragma unroll
  for (int i = 0; i < 8; ++i) sa += sm.a.red[i];
  const float inv = 1.f / fmaxf(sa, 1e-12f);
  if (tid < SS) sm.a.an[tid] = am * inv;
  __syncthreads();
  {  // ctx[k] = sum_s an[s]*val[b][s][k]  (k x s-half over 512 thr)
    const int k = tid & 255, sh = tid >> 8;
    const __half* vp = val16 + ((size_t)b * SS + sh * 200) * 256 + k;
    const float* ap = &sm.a.an[sh * 200];
    float a = 0.f;
#pragma unroll 4
    for (int s = 0; s < 200; ++s)
      a = fmaf(ap[s], __half2float(vp[(size_t)s * 256]), a);
    sm.a.cxp[sh][k] = a;
  }
  __syncthreads();
  if (tid < 128) {
    const float v0 = sm.a.cxp[0][2 * tid] + sm.a.cxp[1][2 * tid];
    const float v1 = sm.a.cxp[0][2 * tid + 1] + sm.a.cxp[1][2 * tid + 1];
    astore_u32(X1n32 + (size_t)b * 512 + 128 + tid, pack2h(v0, v1));
  }
  __syncthreads();
}

// ------------------------------ logits + nll ------------------------------
__device__ __forceinline__ void logits_stage(SM& sm, int b, int t,
                                             const u64* X3n,
                                             const float* __restrict__ WvT,
                                             const float* __restrict__ bv,
                                             const int* __restrict__ target,
                                             const float* __restrict__ tmask,
                                             float& lreg) {
  const int tid = threadIdx.x;
  if (tid < 128) {
    const u64 v = aload_u64(X3n + (size_t)b * 256 + 128 + tid);
    unsigned lo = (unsigned)v, hi = (unsigned)(v >> 32);
    const __half2 h0 = *(const __half2*)&lo, h1 = *(const __half2*)&hi;
    const float2 f0 = __half22float2(h0), f1 = __half22float2(h1);
    sm.g.h3f[tid * 4 + 0] = f0.x;
    sm.g.h3f[tid * 4 + 1] = f0.y;
    sm.g.h3f[tid * 4 + 2] = f1.x;
    sm.g.h3f[tid * 4 + 3] = f1.y;
  }
  __syncthreads();
  {
    const int c = tid & 63, ks = tid >> 6;
    if (c < VV) {
      float a = 0.f;
      const float* hp = &sm.g.h3f[ks * 64];
      const float* wp = WvT + (size_t)(ks * 64) * VV + c;
#pragma unroll 4
      for (int h = 0; h < 64; ++h) a = fmaf(hp[h], wp[h * VV], a);
      sm.g.redl[c * 8 + ks] = a;
    }
  }
  __syncthreads();
  if (tid < VV) {
    const float* rp = &sm.g.redl[tid * 8];
    float l = bv[tid];
#pragma unroll
    for (int k = 0; k < 8; ++k) l += rp[k];
    sm.g.lbuf[tid] = l;
  }
  __syncthreads();
  if (tid == 0) {
    float M = sm.g.lbuf[0];
    for (int v = 1; v < VV; ++v) M = fmaxf(M, sm.g.lbuf[v]);
    float Z = 0.f;
    for (int v = 0; v < VV; ++v) Z += expf(sm.g.lbuf[v] - M);
    const int yy = target[t * BB + b];
    lreg += tmask[t * BB + b] * (-(sm.g.lbuf[yy] - M - logf(Z)));
  }
  __syncthreads();
}

// --------------------------------- main -----------------------------------
__global__ void __launch_bounds__(TPB, 1) kmain(
    const int* __restrict__ target, const float* __restrict__ tmask,
    const float* __restrict__ amask, const float* __restrict__ emb,
    const float* __restrict__ bq, const float* __restrict__ bv,
    const float* __restrict__ cx1, const float* __restrict__ cx2,
    const float* __restrict__ cx3, char* wsb, float* __restrict__ dout) {
  __shared__ SM sm;
  const int wg = blockIdx.x, tid = threadIdx.x;
  unsigned* bar = (unsigned*)(wsb + OBAR);
  const unsigned short* W1 = (const unsigned short*)(wsb + OW16);
  const unsigned short* W2 = W1 + 2097152;
  const unsigned short* W3 = W2 + 2097152;
  const unsigned short* Wq16 = (const unsigned short*)(wsb + OWQ);
  const __half* key16 = (const __half*)(wsb + OKEY);
  const __half* val16 = (const __half*)(wsb + OVAL);
  const float* bs1 = (const float*)(wsb + OBS1);
  const float* bs2 = (const float*)(wsb + OBS2);
  const float* bs3 = (const float*)(wsb + OBS3);
  const float* WvT = (const float*)(wsb + OWVT);
  float* lacc = (float*)(wsb + OLACC);

  const int cgI = wg & 31, b0 = (wg >> 5) * 8;
  float c1r = 0.f, c2r = 0.f, c3r = 0.f;
  if (tid < 128) {
    const int u = (cgI << 4) + (tid & 15);
    c1r = cx1[u];
    c2r = cx2[u];
    c3r = cx3[u];
  }
  float lreg = 0.f;

  for (int t = 0; t < NSTEP; ++t) {
    const int cur = t & 1, nxt = cur ^ 1;
    u64* X1c = (u64*)(wsb + OX1) + (size_t)cur * 16384;
    u64* X1n = (u64*)(wsb + OX1) + (size_t)nxt * 16384;
    u64* X2c = (u64*)(wsb + OX2) + (size_t)cur * 16384;
    u64* X2n = (u64*)(wsb + OX2) + (size_t)nxt * 16384;
    u64* X3c = (u64*)(wsb + OX3) + (size_t)cur * 16384;
    u64* X3n = (u64*)(wsb + OX3) + (size_t)nxt * 16384;

    lstm_stage(sm, cgI, b0, X1c, W1, bs1, c1r, (unsigned*)X2c, 0,
               (unsigned*)X1n, 256);
    gbar(bar, wg);
    lstm_stage(sm, cgI, b0, X2c, W2, bs2, c2r, (unsigned*)X3c, 0,
               (unsigned*)X2n, 256);
    gbar(bar, wg);
    lstm_stage(sm, cgI, b0, X3c, W3, bs3, c3r, (unsigned*)X3n, 256, nullptr,
               0);
    gbar(bar, wg);
    if (wg < 64) {
      attn_stage(sm, wg, t, X3n, Wq16, bq, key16, val16, amask,
                 (unsigned*)X1n, dout);
    } else if (wg < 128) {
      if (t < TT)
        logits_stage(sm, wg - 64, t, X3n, WvT, bv, target, tmask, lreg);
    } else if (wg < 192) {
      const int b = wg - 128;
      if (t < TT && tid < 64) {
        const int y = target[t * BB + b];
        const float4 v = *(const float4*)&emb[(size_t)y * EE + tid * 4];
        astore_u64(X1n + (size_t)b * 256 + tid, pack4h(v));
      }
    }
    gbar(bar, wg);
  }
  if (wg >= 64 && wg < 128 && tid == 0)
    astore_u32((unsigned*)&lacc[wg - 64], __float_as_uint(lreg));
  gbar(bar, wg);
  if (wg == 0 && tid < 64) {
    float v = __uint_as_float(aload_u32((const unsigned*)&lacc[tid]));
    for (int o = 32; o; o >>= 1) v += __shfl_xor(v, o);
    if (tid == 0) dout[0] = v * (1.f / 64.f);
  }
}

// ---------------------------------- init ----------------------------------
__global__ void k_init(const float* emb, const float* Wq, const float* bq,
                       const float* Wv, const float* bih1, const float* bhh1,
                       const float* bih2, const float* bhh2, const float* bih3,
                       const float* bhh3, const float* hx1, const float* hx2,
                       const float* hx3, char* wsb) {
  const int b = blockIdx.x, tid = threadIdx.x;
  __half* X1 = (__half*)(wsb + OX1);
  __half* X2 = (__half*)(wsb + OX2);
  __half* X3 = (__half*)(wsb + OX3);
  __shared__ float hx[HH];
  for (int k = tid; k < HH; k += 256) {
    const float v = hx1[k];
    hx[k] = v;
    X1[b * 1024 + 512 + k] = __float2half(v);
    X2[b * 1024 + 512 + k] = __float2half(hx2[k]);
    X3[b * 1024 + 512 + k] = __float2half(hx3[k]);
  }
  for (int k = tid; k < EE; k += 256) X1[b * 1024 + k] = __float2half(emb[k]);
  __syncthreads();
  for (int c = tid; c < KD; c += 256) {
    float a = bq[c];
    for (int k = 0; k < HH; ++k) a = fmaf(hx[k], Wq[(size_t)c * HH + k], a);
    X1[b * 1024 + 256 + c] = __float2half(a);
  }
  if (b == 0) {
    float* s1 = (float*)(wsb + OBS1);
    float* s2 = (float*)(wsb + OBS2);
    float* s3 = (float*)(wsb + OBS3);
    for (int i = tid; i < 2048; i += 256) {
      s1[i] = bih1[i] + bhh1[i];
      s2[i] = bih2[i] + bhh2[i];
      s3[i] = bih3[i] + bhh3[i];
    }
    float* wvt = (float*)(wsb + OWVT);
    for (int i = tid; i < HH * VV; i += 256) {
      const int h = i / VV, v = i % VV;
      wvt[i] = Wv[(size_t)v * HH + h];
    }
    float* lacc = (float*)(wsb + OLACC);
    for (int i = tid; i < 64; i += 256) lacc[i] = 0.f;
    unsigned* bar = (unsigned*)(wsb + OBAR);
    for (int i = tid; i < 512; i += 256) bar[i] = 0u;
  }
}

// ----------------------------- fp16 staging -------------------------------
__global__ void k_cvt(const float* key, const float* val, const float* Wq,
                      const float* Wih1, const float* Whh1, const float* Wih2,
                      const float* Whh2, const float* Wih3, const float* Whh3,
                      char* wsb) {
  const int blk = blockIdx.x, tid = threadIdx.x;
  if (blk < 6144) {  // W16: layer, row -> [Wih row | Whh row] fp16
    const int layer = blk >> 11, R = blk & 2047;
    const float* Wih = (layer == 0) ? Wih1 : ((layer == 1) ? Wih2 : Wih3);
    const float* Whh = (layer == 0) ? Whh1 : ((layer == 1) ? Whh2 : Whh3);
    __half* dst = (__half*)(wsb + OW16) + (size_t)layer * 2097152 +
                  (size_t)R * 1024;
    const int k0 = tid * 4;
    const float* src = (k0 < 512) ? &Wih[(size_t)R * 512 + k0]
                                  : &Whh[(size_t)R * 512 + (k0 - 512)];
    const float4 v = *(const float4*)src;
    dst[k0 + 0] = __float2half(v.x);
    dst[k0 + 1] = __float2half(v.y);
    dst[k0 + 2] = __float2half(v.z);
    dst[k0 + 3] = __float2half(v.w);
  } else if (blk < 7744) {  // key16 flat
    const size_t base = (size_t)(blk - 6144) * 4096 + (size_t)tid * 16;
    __half* dst = (__half*)(wsb + OKEY);
#pragma unroll
    for (int j = 0; j < 4; ++j) {
      const float4 v = *(const float4*)&key[base + j * 4];
      dst[base + j * 4 + 0] = __float2half(v.x);
      dst[base + j * 4 + 1] = __float2half(v.y);
      dst[base + j * 4 + 2] = __float2half(v.z);
      dst[base + j * 4 + 3] = __float2half(v.w);
    }
  } else if (blk < 9344) {  // val16 flat
    const size_t base = (size_t)(blk - 7744) * 4096 + (size_t)tid * 16;
    __half* dst = (__half*)(wsb + OVAL);
#pragma unroll
    for (int j = 0; j < 4; ++j) {
      const float4 v = *(const float4*)&val[base + j * 4];
      dst[base + j * 4 + 0] = __float2half(v.x);
      dst[base + j * 4 + 1] = __float2half(v.y);
      dst[base + j * 4 + 2] = __float2half(v.z);
      dst[base + j * 4 + 3] = __float2half(v.w);
    }
  } else {  // Wq16 flat [256][512]
    const size_t base = (size_t)(blk - 9344) * 4096 + (size_t)tid * 16;
    __half* dst = (__half*)(wsb + OWQ);
#pragma unroll
    for (int j = 0; j < 4; ++j) {
      const float4 v = *(const float4*)&Wq[base + j * 4];
      dst[base + j * 4 + 0] = __float2half(v.x);
      dst[base + j * 4 + 1] = __float2half(v.y);
      dst[base + j * 4 + 2] = __float2half(v.z);
      dst[base + j * 4 + 3] = __float2half(v.w);
    }
  }
}

// --------------------------------- launch ---------------------------------
extern "C" void kernel_launch(void* const* d_in, const int* in_sizes, int n_in,
                              void* d_out, int out_size, void* d_ws,
                              size_t ws_size, hipStream_t stream) {
  const int* target = (const int*)d_in[0];
  const float* tmask = (const float*)d_in[1];
  const float* key = (const float*)d_in[2];
  const float* val = (const float*)d_in[3];
  const float* amask = (const float*)d_in[4];
  const float* emb = (const float*)d_in[5];
  const float* Wih1 = (const float*)d_in[6];
  const float* Whh1 = (const float*)d_in[7];
  const float* bih1 = (const float*)d_in[8];
  const float* bhh1 = (const float*)d_in[9];
  const float* Wih2 = (const float*)d_in[10];
  const float* Whh2 = (const float*)d_in[11];
  const float* bih2 = (const float*)d_in[12];
  const float* bhh2 = (const float*)d_in[13];
  const float* Wih3 = (const float*)d_in[14];
  const float* Whh3 = (const float*)d_in[15];
  const float* bih3 = (const float*)d_in[16];
  const float* bhh3 = (const float*)d_in[17];
  const float* Wq = (const float*)d_in[18];
  const float* bq = (const float*)d_in[19];
  const float* Wv = (const float*)d_in[20];
  const float* bv = (const float*)d_in[21];
  const float* hx1 = (const float*)d_in[22];
  const float* cx1 = (const float*)d_in[23];
  const float* hx2 = (const float*)d_in[24];
  const float* cx2 = (const float*)d_in[25];
  const float* hx3 = (const float*)d_in[26];
  const float* cx3 = (const float*)d_in[27];
  float* out = (float*)d_out;
  char* wsb = (char*)d_ws;

  hipLaunchKernelGGL(k_init, dim3(64), dim3(256), 0, stream, emb, Wq, bq, Wv,
                     bih1, bhh1, bih2, bhh2, bih3, bhh3, hx1, hx2, hx3, wsb);
  hipLaunchKernelGGL(k_cvt, dim3(9376), dim3(256), 0, stream, key, val, Wq,
                     Wih1, Whh1, Wih2, Whh2, Wih3, Whh3, wsb);

  void* args[] = {(void*)&target, (void*)&tmask, (void*)&amask, (void*)&emb,
                  (void*)&bq,     (void*)&bv,    (void*)&cx1,   (void*)&cx2,
                  (void*)&cx3,    (void*)&wsb,   (void*)&out};
  hipLaunchCooperativeKernel((const void*)kmain, dim3(NWG), dim3(TPB), args, 0,
                             stream);
}

// Round 7
// 17719.086 us; speedup vs baseline: 1.6166x; 1.6166x over previous
//
#include <hip/hip_runtime.h>
#include <hip/hip_fp16.h>

// SpellerModel round 7: persistent cooperative kernel, 256 WGs x 512 thr.
// vs round 6: (1) XCD-affine work claim (getreg XCC_ID + CAS claim table) so
// W-slices/kv stay L2-resident per XCD; (2) val16 via nontemporal loads (no
// L2 alloc); (3) LSTM register-tiled 4 rows x 4 batches x K/16 per thread.
// Cross-WG data still via atomic RMW only (exchange stores, or-0 loads).

#define BB 64
#define TT 200
#define SS 400
#define VV 34
#define EE 256
#define HH 512
#define KD 256
#define NSTEP 201
#define NWG 256
#define TPB 512

typedef unsigned long long u64;

// ---- workspace byte offsets ----
#define OX1   0u            // halves [2][64][1024] (emb|ctx|h1)
#define OX2   262144u       // halves [2][64][1024] (h1|h2)
#define OX3   524288u       // halves [2][64][1024] (h2|h3)
#define OBS1  786432u       // f32 [2048] bih+bhh
#define OBS2  794624u
#define OBS3  802816u
#define OWVT  811008u       // f32 [512][34]
#define OLACC 880640u       // f32 [64]
#define OBAR  880896u       // u32 [1024] barrier + cnt8 + claim256
#define OW16  1048576u      // fp16 [3][2048][1024] (Wih|Whh per row)
#define OWQ   13631488u     // fp16 [256][512]
#define OKEY  13893632u     // fp16 [64][400][256]
#define OVAL  27000832u     // fp16 [64][400][256]

// ---------------- coherent-point RMW helpers ------------------------------
__device__ __forceinline__ unsigned aload_u32(const unsigned* p) {
  unsigned v;
  asm volatile(
      "global_atomic_or %0, %1, %2, off sc0 sc1\n\t"
      "s_waitcnt vmcnt(0)"
      : "=&v"(v)
      : "v"(p), "v"(0u)
      : "memory");
  return v;
}
__device__ __forceinline__ u64 aload_u64(const u64* p) {
  u64 v;
  asm volatile(
      "global_atomic_or_x2 %0, %1, %2, off sc0 sc1\n\t"
      "s_waitcnt vmcnt(0)"
      : "=&v"(v)
      : "v"(p), "v"(0ull)
      : "memory");
  return v;
}
__device__ __forceinline__ void aload4_u64(const u64* p0, const u64* p1,
                                           const u64* p2, const u64* p3,
                                           u64& r0, u64& r1, u64& r2,
                                           u64& r3) {
  asm volatile(
      "global_atomic_or_x2 %0, %4, %8, off sc0 sc1\n\t"
      "global_atomic_or_x2 %1, %5, %8, off sc0 sc1\n\t"
      "global_atomic_or_x2 %2, %6, %8, off sc0 sc1\n\t"
      "global_atomic_or_x2 %3, %7, %8, off sc0 sc1\n\t"
      "s_waitcnt vmcnt(0)"
      : "=&v"(r0), "=&v"(r1), "=&v"(r2), "=&v"(r3)
      : "v"(p0), "v"(p1), "v"(p2), "v"(p3), "v"(0ull)
      : "memory");
}
__device__ __forceinline__ void astore_u32(unsigned* p, unsigned v) {
  __hip_atomic_exchange(p, v, __ATOMIC_RELAXED, __HIP_MEMORY_SCOPE_AGENT);
}
__device__ __forceinline__ void astore_u64(u64* p, u64 v) {
  __hip_atomic_exchange(p, v, __ATOMIC_RELAXED, __HIP_MEMORY_SCOPE_AGENT);
}

// ---------------- fp16 pack / dot / nt helpers ----------------------------
__device__ __forceinline__ unsigned pack2h(float a, float b) {
  return (unsigned)__half_as_ushort(__float2half(a)) |
         ((unsigned)__half_as_ushort(__float2half(b)) << 16);
}
__device__ __forceinline__ u64 pack4h(float4 v) {
  return (u64)pack2h(v.x, v.y) | ((u64)pack2h(v.z, v.w) << 32);
}
__device__ __forceinline__ float dot2acc(unsigned x, unsigned w, float acc) {
#if __has_builtin(__builtin_amdgcn_fdot2)
  typedef _Float16 h2 __attribute__((ext_vector_type(2)));
  union C { unsigned u; h2 h; };
  C a, b;
  a.u = x;
  b.u = w;
  return __builtin_amdgcn_fdot2(a.h, b.h, acc, false);
#else
  const __half2 ha = *(const __half2*)&x, hb = *(const __half2*)&w;
  const float2 fa = __half22float2(ha), fb = __half22float2(hb);
  return fmaf(fa.y, fb.y, fmaf(fa.x, fb.x, acc));
#endif
}
__device__ __forceinline__ float ntldh(const __half* p) {
  unsigned short u = __builtin_nontemporal_load((const unsigned short*)p);
  union { unsigned short s; __half h; } c;
  c.s = u;
  return __half2float(c.h);
}

// ---------------------------- LDS union -----------------------------------
struct __align__(16) SM {
  union {
    union {
      u64 xs[8 * 258];                               // x staged, pitch 258 u64
      struct { float red[256 * 17]; float gates[8 * 65]; } r;
    } l;
    struct {
      unsigned h3u[256];
      float qp[2][256];
      float qf[256];
      unsigned qh[128];
      float an[SS];
      float red[8];
      float cxp[2][256];
    } a;
    struct { float h3f[512]; float redl[VV * 8]; float lbuf[VV]; } g;
  };
};

// ------------------------- fence-free global barrier ----------------------
__device__ __forceinline__ void gbar(unsigned* bar, int wg) {
  __syncthreads();
  if (threadIdx.x == 0) {
    unsigned* cnt = bar + (wg >> 5) * 16;
    unsigned* gen = bar + 128 + (wg >> 5) * 16;
    unsigned* rc = bar + 256;
    unsigned* rgen = bar + 272;
    const unsigned g0 = aload_u32(gen);
    if (__hip_atomic_fetch_add(cnt, 1u, __ATOMIC_RELAXED,
                               __HIP_MEMORY_SCOPE_AGENT) == 31u) {
      const unsigned r0 = aload_u32(rgen);
      if (__hip_atomic_fetch_add(rc, 1u, __ATOMIC_RELAXED,
                                 __HIP_MEMORY_SCOPE_AGENT) == 7u) {
        __hip_atomic_fetch_add(rc, (unsigned)-8, __ATOMIC_RELAXED,
                               __HIP_MEMORY_SCOPE_AGENT);
        __hip_atomic_fetch_add(rgen, 1u, __ATOMIC_RELAXED,
                               __HIP_MEMORY_SCOPE_AGENT);
      } else {
        while (aload_u32(rgen) == r0) __builtin_amdgcn_s_sleep(1);
      }
      __hip_atomic_fetch_add(cnt, (unsigned)-32, __ATOMIC_RELAXED,
                             __HIP_MEMORY_SCOPE_AGENT);
      __hip_atomic_fetch_add(gen, 1u, __ATOMIC_RELAXED,
                             __HIP_MEMORY_SCOPE_AGENT);
    } else {
      while (aload_u32(gen) == g0) __builtin_amdgcn_s_sleep(1);
    }
    asm volatile("" ::: "memory");
  }
  __syncthreads();
}

// ------------------------------- LSTM stage -------------------------------
// WG covers cgI (16 units, 64 gate rows) x 8 batches (b0..b0+7).
// Thread tid = ks*32 + rg*2 + bg: 4 rows (rg*4..+3) x 4 batches (bg*4..+3),
// K-slice 64 halves (ks of 16). x from LDS (padded pitch, broadcast), W L2.
__device__ __forceinline__ void lstm_stage(SM& sm, int cgI, int b0,
                                           const u64* Xc,
                                           const unsigned short* W16,
                                           const float* __restrict__ bsum,
                                           float& creg, unsigned* d1, int o1,
                                           unsigned* d2, int o2) {
  const int tid = threadIdx.x;
  {  // stage x[b0..b0+7][0:1024] halves via RMW into padded LDS
    const u64* src = Xc + (size_t)b0 * 256;
    u64 r0, r1, r2, r3;
    aload4_u64(src + tid, src + tid + 512, src + tid + 1024, src + tid + 1536,
               r0, r1, r2, r3);
    sm.l.xs[((tid) >> 8) * 258 + ((tid)&255)] = r0;
    sm.l.xs[((tid + 512) >> 8) * 258 + ((tid + 512) & 255)] = r1;
    sm.l.xs[((tid + 1024) >> 8) * 258 + ((tid + 1024) & 255)] = r2;
    sm.l.xs[((tid + 1536) >> 8) * 258 + ((tid + 1536) & 255)] = r3;
  }
  __syncthreads();
  const int g = tid & 31, ks = tid >> 5;
  const int rg = g >> 1, bg = g & 1;
  const int R0 = ((rg >> 2) << 9) + (cgI << 4) + ((rg & 3) << 2);
  const unsigned* wb = (const unsigned*)W16;
  const unsigned* wp0 = wb + (size_t)(R0 + 0) * 512 + ks * 32;
  const unsigned* wp1 = wb + (size_t)(R0 + 1) * 512 + ks * 32;
  const unsigned* wp2 = wb + (size_t)(R0 + 2) * 512 + ks * 32;
  const unsigned* wp3 = wb + (size_t)(R0 + 3) * 512 + ks * 32;
  const unsigned* xl = (const unsigned*)sm.l.xs;
  const int xbase = bg * 4 * 516 + ks * 32;
  float acc[4][4];
#pragma unroll
  for (int i = 0; i < 4; ++i)
#pragma unroll
    for (int j = 0; j < 4; ++j) acc[i][j] = 0.f;
#pragma unroll
  for (int kk = 0; kk < 8; ++kk) {
    uint4 wv[4], xv[4];
    wv[0] = *(const uint4*)&wp0[kk * 4];
    wv[1] = *(const uint4*)&wp1[kk * 4];
    wv[2] = *(const uint4*)&wp2[kk * 4];
    wv[3] = *(const uint4*)&wp3[kk * 4];
#pragma unroll
    for (int j = 0; j < 4; ++j)
      xv[j] = *(const uint4*)&xl[xbase + j * 516 + kk * 4];
#pragma unroll
    for (int i = 0; i < 4; ++i) {
#pragma unroll
      for (int j = 0; j < 4; ++j) {
        acc[i][j] = dot2acc(xv[j].x, wv[i].x, acc[i][j]);
        acc[i][j] = dot2acc(xv[j].y, wv[i].y, acc[i][j]);
        acc[i][j] = dot2acc(xv[j].z, wv[i].z, acc[i][j]);
        acc[i][j] = dot2acc(xv[j].w, wv[i].w, acc[i][j]);
      }
    }
  }
  __syncthreads();  // xs dead; red overlays
  // ks-pair reduce in-wave, then partials to LDS
#pragma unroll
  for (int i = 0; i < 4; ++i)
#pragma unroll
    for (int j = 0; j < 4; ++j) acc[i][j] += __shfl_xor(acc[i][j], 32);
  if ((tid & 32) == 0) {
    const int wtid = (tid >> 6) * 32 + g;  // 0..255
#pragma unroll
    for (int i = 0; i < 4; ++i)
#pragma unroll
      for (int j = 0; j < 4; ++j)
        sm.l.r.red[wtid * 17 + i * 4 + j] = acc[i][j];
  }
  __syncthreads();
  {  // final: output o = r*8 + b, sum 8 kp-partials
    const int o = tid;
    const int org = o >> 5, oi = (o >> 3) & 3, obg = (o >> 2) & 1, oj = o & 3;
    const int gslot = org * 2 + obg, idx = oi * 4 + oj;
    float s = 0.f;
#pragma unroll
    for (int kp = 0; kp < 8; ++kp)
      s += sm.l.r.red[(kp * 32 + gslot) * 17 + idx];
    const int r = o >> 3, bl = o & 7;
    sm.l.r.gates[bl * 65 + r] = s;
  }
  __syncthreads();
  if (tid < 128) {
    const int bl = tid >> 4, uu = tid & 15;
    const int u = (cgI << 4) + uu;
    const float* gts = &sm.l.r.gates[bl * 65];
    const float gi = gts[uu] + bsum[u];
    const float gf = gts[16 + uu] + bsum[512 + u];
    const float gG = gts[32 + uu] + bsum[1024 + u];
    const float go = gts[48 + uu] + bsum[1536 + u];
    const float si = 1.f / (1.f + expf(-gi));
    const float sf = 1.f / (1.f + expf(-gf));
    const float so = 1.f / (1.f + expf(-go));
    const float cn = sf * creg + si * tanhf(gG);
    const float hn = so * tanhf(cn);
    creg = cn;
    const unsigned hb = (unsigned)__half_as_ushort(__float2half(hn));
    const unsigned ob = __shfl_down(hb, 1);
    if ((uu & 1) == 0) {
      const unsigned pk = hb | (ob << 16);
      const size_t off = (size_t)(b0 + bl) * 512 + (u >> 1);
      astore_u32(d1 + off + o1, pk);
      if (d2) astore_u32(d2 + off + o2, pk);
    }
  }
  __syncthreads();
}

// --------------------- attention (incl. its own q) ------------------------
__device__ __forceinline__ void attn_stage(
    SM& sm, int b, int t, const u64* X3n, const unsigned short* Wq16,
    const float* __restrict__ bq, const __half* __restrict__ key16,
    const __half* __restrict__ val16, const float* __restrict__ amask,
    unsigned* X1n32, float* __restrict__ dout) {
  const int tid = threadIdx.x;
  if (tid < 128) {
    const u64 v = aload_u64(X3n + (size_t)b * 256 + 128 + tid);
    *(u64*)&sm.a.h3u[(size_t)tid * 2] = v;
  }
  __syncthreads();
  {  // q = h3 @ Wq.T
    const int c = tid & 255, kh = tid >> 8;
    const unsigned* wq = (const unsigned*)Wq16 + (size_t)c * 256 + kh * 128;
    const unsigned* hp = &sm.a.h3u[kh * 128];
    float a = 0.f;
#pragma unroll 8
    for (int i = 0; i < 32; ++i) {
      const uint4 w4 = *(const uint4*)&wq[i * 4];
      const uint4 x4 = *(const uint4*)&hp[i * 4];
      a = dot2acc(x4.x, w4.x, a);
      a = dot2acc(x4.y, w4.y, a);
      a = dot2acc(x4.z, w4.z, a);
      a = dot2acc(x4.w, w4.w, a);
    }
    sm.a.qp[kh][c] = a;
  }
  __syncthreads();
  if (tid < 256) sm.a.qf[tid] = sm.a.qp[0][tid] + sm.a.qp[1][tid] + bq[tid];
  __syncthreads();
  if (tid < 128) sm.a.qh[tid] = pack2h(sm.a.qf[2 * tid], sm.a.qf[2 * tid + 1]);
  __syncthreads();
  float e = -1e30f;
  if (tid < SS) {
    const unsigned* kp = (const unsigned*)key16 + ((size_t)b * SS + tid) * 128;
    float a = 0.f;
#pragma unroll 8
    for (int i = 0; i < 32; ++i) {
      const uint4 k4 = *(const uint4*)&kp[i * 4];
      const uint4 q4 = *(const uint4*)&sm.a.qh[i * 4];
      a = dot2acc(q4.x, k4.x, a);
      a = dot2acc(q4.y, k4.y, a);
      a = dot2acc(q4.z, k4.z, a);
      a = dot2acc(q4.w, k4.w, a);
    }
    e = a;
  }
  float m = e;
  for (int o = 32; o; o >>= 1) m = fmaxf(m, __shfl_xor(m, o));
  if ((tid & 63) == 0) sm.a.red[tid >> 6] = m;
  __syncthreads();
  m = sm.a.red[0];
#pragma unroll
  for (int i = 1; i < 8; ++i) m = fmaxf(m, sm.a.red[i]);
  __syncthreads();
  const float p = (tid < SS) ? expf(e - m) : 0.f;
  float z = p;
  for (int o = 32; o; o >>= 1) z += __shfl_xor(z, o);
  if ((tid & 63) == 0) sm.a.red[tid >> 6] = z;
  __syncthreads();
  z = 0.f;
#pragma unroll
  for (int i = 0; i < 8; ++i) z += sm.a.red[i];
  __syncthreads();
  const float at = p / z;
  if (b == 0 && tid < SS) dout[1 + (size_t)t * SS + tid] = at;
  const float am = (tid < SS) ? at * amask[(size_t)b * SS + tid] : 0.f;
  float sa = fabsf(am);
  for (int o = 32; o; o >>= 1) sa += __shfl_xor(sa, o);
  if ((tid & 63) == 0) sm.a.red[tid >> 6] = sa;
  __syncthreads();
  sa = 0.f;
#pragma unroll
  for (int i = 0; i < 8; ++i) sa += sm.a.red[i];
  const float inv = 1.f / fmaxf(sa, 1e-12f);
  if (tid < SS) sm.a.an[tid] = am * inv;
  __syncthreads();
  {  // ctx[k] = sum_s an[s]*val[b][s][k] — val nontemporal (no L2 alloc)
    const int k = tid & 255, sh = tid >> 8;
    const __half* vp = val16 + ((size_t)b * SS + sh * 200) * 256 + k;
    const float* ap = &sm.a.an[sh * 200];
    float a = 0.f;
#pragma unroll 4
    for (int s = 0; s < 200; ++s)
      a = fmaf(ap[s], ntldh(vp + (size_t)s * 256), a);
    sm.a.cxp[sh][k] = a;
  }
  __syncthreads();
  if (tid < 128) {
    const float v0 = sm.a.cxp[0][2 * tid] + sm.a.cxp[1][2 * tid];
    const float v1 = sm.a.cxp[0][2 * tid + 1] + sm.a.cxp[1][2 * tid + 1];
    astore_u32(X1n32 + (size_t)b * 512 + 128 + tid, pack2h(v0, v1));
  }
  __syncthreads();
}

// ------------------------------ logits + nll ------------------------------
__device__ __forceinline__ void logits_stage(SM& sm, int b, int t,
                                             const u64* X3n,
                                             const float* __restrict__ WvT,
                                             const float* __restrict__ bv,
                                             const int* __restrict__ target,
                                             const float* __restrict__ tmask,
                                             float& lreg) {
  const int tid = threadIdx.x;
  if (tid < 128) {
    const u64 v = aload_u64(X3n + (size_t)b * 256 + 128 + tid);
    unsigned lo = (unsigned)v, hi = (unsigned)(v >> 32);
    const __half2 h0 = *(const __half2*)&lo, h1 = *(const __half2*)&hi;
    const float2 f0 = __half22float2(h0), f1 = __half22float2(h1);
    sm.g.h3f[tid * 4 + 0] = f0.x;
    sm.g.h3f[tid * 4 + 1] = f0.y;
    sm.g.h3f[tid * 4 + 2] = f1.x;
    sm.g.h3f[tid * 4 + 3] = f1.y;
  }
  __syncthreads();
  {
    const int c = tid & 63, ks = tid >> 6;
    if (c < VV) {
      float a = 0.f;
      const float* hp = &sm.g.h3f[ks * 64];
      const float* wp = WvT + (size_t)(ks * 64) * VV + c;
#pragma unroll 4
      for (int h = 0; h < 64; ++h) a = fmaf(hp[h], wp[h * VV], a);
      sm.g.redl[c * 8 + ks] = a;
    }
  }
  __syncthreads();
  if (tid < VV) {
    const float* rp = &sm.g.redl[tid * 8];
    float l = bv[tid];
#pragma unroll
    for (int k = 0; k < 8; ++k) l += rp[k];
    sm.g.lbuf[tid] = l;
  }
  __syncthreads();
  if (tid == 0) {
    float M = sm.g.lbuf[0];
    for (int v = 1; v < VV; ++v) M = fmaxf(M, sm.g.lbuf[v]);
    float Z = 0.f;
    for (int v = 0; v < VV; ++v) Z += expf(sm.g.lbuf[v] - M);
    const int yy = target[t * BB + b];
    lreg += tmask[t * BB + b] * (-(sm.g.lbuf[yy] - M - logf(Z)));
  }
  __syncthreads();
}

// --------------------------------- main -----------------------------------
__global__ void __launch_bounds__(TPB, 1) kmain(
    const int* __restrict__ target, const float* __restrict__ tmask,
    const float* __restrict__ amask, const float* __restrict__ emb,
    const float* __restrict__ bq, const float* __restrict__ bv,
    const float* __restrict__ cx1, const float* __restrict__ cx2,
    const float* __restrict__ cx3, char* wsb, float* __restrict__ dout) {
  __shared__ SM sm;
  __shared__ int s_wid;
  const int wg = blockIdx.x, tid = threadIdx.x;
  unsigned* bar = (unsigned*)(wsb + OBAR);
  const unsigned short* W1 = (const unsigned short*)(wsb + OW16);
  const unsigned short* W2 = W1 + 2097152;
  const unsigned short* W3 = W2 + 2097152;
  const unsigned short* Wq16 = (const unsigned short*)(wsb + OWQ);
  const __half* key16 = (const __half*)(wsb + OKEY);
  const __half* val16 = (const __half*)(wsb + OVAL);
  const float* bs1 = (const float*)(wsb + OBS1);
  const float* bs2 = (const float*)(wsb + OBS2);
  const float* bs3 = (const float*)(wsb + OBS3);
  const float* WvT = (const float*)(wsb + OWVT);
  float* lacc = (float*)(wsb + OLACC);

  // ---- XCD-affine workid claim (correct under any dispatch pattern) ----
  if (tid == 0) {
    unsigned xcc = 0;
    asm volatile("s_getreg_b32 %0, hwreg(20, 0, 32)" : "=s"(xcc));
    xcc &= 7u;
    unsigned* cnt = bar + 288;
    unsigned* claim = bar + 320;
    int wid = -1;
    const unsigned r = __hip_atomic_fetch_add(&cnt[xcc], 1u, __ATOMIC_RELAXED,
                                              __HIP_MEMORY_SCOPE_AGENT);
    if (r < 32u) {
      const int cand = (int)(xcc * 32u + r);
      if (__hip_atomic_exchange(&claim[cand], 1u, __ATOMIC_RELAXED,
                                __HIP_MEMORY_SCOPE_AGENT) == 0u)
        wid = cand;
    }
    for (int i = 0; wid < 0 && i < 256; ++i)
      if (__hip_atomic_exchange(&claim[i], 1u, __ATOMIC_RELAXED,
                                __HIP_MEMORY_SCOPE_AGENT) == 0u)
        wid = i;
    s_wid = wid;
  }
  __syncthreads();
  const int Wd = s_wid;
  const int xcls = Wd >> 5, lw = Wd & 31;
  const int cgI = xcls * 4 + (lw & 3);
  const int b0 = ((lw >> 2) & 7) * 8;

  float c1r = 0.f, c2r = 0.f, c3r = 0.f;
  if (tid < 128) {
    const int u = (cgI << 4) + (tid & 15);
    c1r = cx1[u];
    c2r = cx2[u];
    c3r = cx3[u];
  }
  float lreg = 0.f;

  for (int t = 0; t < NSTEP; ++t) {
    const int cur = t & 1, nxt = cur ^ 1;
    u64* X1c = (u64*)(wsb + OX1) + (size_t)cur * 16384;
    u64* X1n = (u64*)(wsb + OX1) + (size_t)nxt * 16384;
    u64* X2c = (u64*)(wsb + OX2) + (size_t)cur * 16384;
    u64* X2n = (u64*)(wsb + OX2) + (size_t)nxt * 16384;
    u64* X3c = (u64*)(wsb + OX3) + (size_t)cur * 16384;
    u64* X3n = (u64*)(wsb + OX3) + (size_t)nxt * 16384;

    lstm_stage(sm, cgI, b0, X1c, W1, bs1, c1r, (unsigned*)X2c, 0,
               (unsigned*)X1n, 256);
    gbar(bar, wg);
    lstm_stage(sm, cgI, b0, X2c, W2, bs2, c2r, (unsigned*)X3c, 0,
               (unsigned*)X2n, 256);
    gbar(bar, wg);
    lstm_stage(sm, cgI, b0, X3c, W3, bs3, c3r, (unsigned*)X3n, 256, nullptr,
               0);
    gbar(bar, wg);
    if (lw < 8) {
      attn_stage(sm, xcls * 8 + lw, t, X3n, Wq16, bq, key16, val16, amask,
                 (unsigned*)X1n, dout);
    } else if (lw < 16) {
      if (t < TT)
        logits_stage(sm, xcls * 8 + lw - 8, t, X3n, WvT, bv, target, tmask,
                     lreg);
    } else if (lw < 24) {
      const int b = xcls * 8 + lw - 16;
      if (t < TT && tid < 64) {
        const int y = target[t * BB + b];
        const float4 v = *(const float4*)&emb[(size_t)y * EE + tid * 4];
        astore_u64(X1n + (size_t)b * 256 + tid, pack4h(v));
      }
    }
    gbar(bar, wg);
  }
  if (lw >= 8 && lw < 16 && tid == 0)
    astore_u32((unsigned*)&lacc[xcls * 8 + lw - 8], __float_as_uint(lreg));
  gbar(bar, wg);
  if (Wd == 0 && tid < 64) {
    float v = __uint_as_float(aload_u32((const unsigned*)&lacc[tid]));
    for (int o = 32; o; o >>= 1) v += __shfl_xor(v, o);
    if (tid == 0) dout[0] = v * (1.f / 64.f);
  }
}

// ---------------------------------- init ----------------------------------
__global__ void k_init(const float* emb, const float* Wq, const float* bq,
                       const float* Wv, const float* bih1, const float* bhh1,
                       const float* bih2, const float* bhh2, const float* bih3,
                       const float* bhh3, const float* hx1, const float* hx2,
                       const float* hx3, char* wsb) {
  const int b = blockIdx.x, tid = threadIdx.x;
  __half* X1 = (__half*)(wsb + OX1);
  __half* X2 = (__half*)(wsb + OX2);
  __half* X3 = (__half*)(wsb + OX3);
  __shared__ float hx[HH];
  for (int k = tid; k < HH; k += 256) {
    const float v = hx1[k];
    hx[k] = v;
    X1[b * 1024 + 512 + k] = __float2half(v);
    X2[b * 1024 + 512 + k] = __float2half(hx2[k]);
    X3[b * 1024 + 512 + k] = __float2half(hx3[k]);
  }
  for (int k = tid; k < EE; k += 256) X1[b * 1024 + k] = __float2half(emb[k]);
  __syncthreads();
  for (int c = tid; c < KD; c += 256) {
    float a = bq[c];
    for (int k = 0; k < HH; ++k) a = fmaf(hx[k], Wq[(size_t)c * HH + k], a);
    X1[b * 1024 + 256 + c] = __float2half(a);
  }
  if (b == 0) {
    float* s1 = (float*)(wsb + OBS1);
    float* s2 = (float*)(wsb + OBS2);
    float* s3 = (float*)(wsb + OBS3);
    for (int i = tid; i < 2048; i += 256) {
      s1[i] = bih1[i] + bhh1[i];
      s2[i] = bih2[i] + bhh2[i];
      s3[i] = bih3[i] + bhh3[i];
    }
    float* wvt = (float*)(wsb + OWVT);
    for (int i = tid; i < HH * VV; i += 256) {
      const int h = i / VV, v = i % VV;
      wvt[i] = Wv[(size_t)v * HH + h];
    }
    float* lacc = (float*)(wsb + OLACC);
    for (int i = tid; i < 64; i += 256) lacc[i] = 0.f;
    unsigned* bar = (unsigned*)(wsb + OBAR);
    for (int i = tid; i < 1024; i += 256) bar[i] = 0u;
  }
}

// ----------------------------- fp16 staging -------------------------------
__global__ void k_cvt(const float* key, const float* val, const float* Wq,
                      const float* Wih1, const float* Whh1, const float* Wih2,
                      const float* Whh2, const float* Wih3, const float* Whh3,
                      char* wsb) {
  const int blk = blockIdx.x, tid = threadIdx.x;
  if (blk < 6144) {  // W16: layer, row -> [Wih row | Whh row] fp16
    const int layer = blk >> 11, R = blk & 2047;
    const float* Wih = (layer == 0) ? Wih1 : ((layer == 1) ? Wih2 : Wih3);
    const float* Whh = (layer == 0) ? Whh1 : ((layer == 1) ? Whh2 : Whh3);
    __half* dst = (__half*)(wsb + OW16) + (size_t)layer * 2097152 +
                  (size_t)R * 1024;
    const int k0 = tid * 4;
    const float* src = (k0 < 512) ? &Wih[(size_t)R * 512 + k0]
                                  : &Whh[(size_t)R * 512 + (k0 - 512)];
    const float4 v = *(const float4*)src;
    dst[k0 + 0] = __float2half(v.x);
    dst[k0 + 1] = __float2half(v.y);
    dst[k0 + 2] = __float2half(v.z);
    dst[k0 + 3] = __float2half(v.w);
  } else if (blk < 7744) {  // key16 flat
    const size_t base = (size_t)(blk - 6144) * 4096 + (size_t)tid * 16;
    __half* dst = (__half*)(wsb + OKEY);
#pragma unroll
    for (int j = 0; j < 4; ++j) {
      const float4 v = *(const float4*)&key[base + j * 4];
      dst[base + j * 4 + 0] = __float2half(v.x);
      dst[base + j * 4 + 1] = __float2half(v.y);
      dst[base + j * 4 + 2] = __float2half(v.z);
      dst[base + j * 4 + 3] = __float2half(v.w);
    }
  } else if (blk < 9344) {  // val16 flat
    const size_t base = (size_t)(blk - 7744) * 4096 + (size_t)tid * 16;
    __half* dst = (__half*)(wsb + OVAL);
#pragma unroll
    for (int j = 0; j < 4; ++j) {
      const float4 v = *(const float4*)&val[base + j * 4];
      dst[base + j * 4 + 0] = __float2half(v.x);
      dst[base + j * 4 + 1] = __float2half(v.y);
      dst[base + j * 4 + 2] = __float2half(v.z);
      dst[base + j * 4 + 3] = __float2half(v.w);
    }
  } else {  // Wq16 flat [256][512]
    const size_t base = (size_t)(blk - 9344) * 4096 + (size_t)tid * 16;
    __half* dst = (__half*)(wsb + OWQ);
#pragma unroll
    for (int j = 0; j < 4; ++j) {
      const float4 v = *(const float4*)&Wq[base + j * 4];
      dst[base + j * 4 + 0] = __float2half(v.x);
      dst[base + j * 4 + 1] = __float2half(v.y);
      dst[base + j * 4 + 2] = __float2half(v.z);
      dst[base + j * 4 + 3] = __float2half(v.w);
    }
  }
}

// --------------------------------- launch ---------------------------------
extern "C" void kernel_launch(void* const* d_in, const int* in_sizes, int n_in,
                              void* d_out, int out_size, void* d_ws,
                              size_t ws_size, hipStream_t stream) {
  const int* target = (const int*)d_in[0];
  const float* tmask = (const float*)d_in[1];
  const float* key = (const float*)d_in[2];
  const float* val = (const float*)d_in[3];
  const float* amask = (const float*)d_in[4];
  const float* emb = (const float*)d_in[5];
  const float* Wih1 = (const float*)d_in[6];
  const float* Whh1 = (const float*)d_in[7];
  const float* bih1 = (const float*)d_in[8];
  const float* bhh1 = (const float*)d_in[9];
  const float* Wih2 = (const float*)d_in[10];
  const float* Whh2 = (const float*)d_in[11];
  const float* bih2 = (const float*)d_in[12];
  const float* bhh2 = (const float*)d_in[13];
  const float* Wih3 = (const float*)d_in[14];
  const float* Whh3 = (const float*)d_in[15];
  const float* bih3 = (const float*)d_in[16];
  const float* bhh3 = (const float*)d_in[17];
  const float* Wq = (const float*)d_in[18];
  const float* bq = (const float*)d_in[19];
  const float* Wv = (const float*)d_in[20];
  const float* bv = (const float*)d_in[21];
  const float* hx1 = (const float*)d_in[22];
  const float* cx1 = (const float*)d_in[23];
  const float* hx2 = (const float*)d_in[24];
  const float* cx2 = (const float*)d_in[25];
  const float* hx3 = (const float*)d_in[26];
  const float* cx3 = (const float*)d_in[27];
  float* out = (float*)d_out;
  char* wsb = (char*)d_ws;

  hipLaunchKernelGGL(k_init, dim3(64), dim3(256), 0, stream, emb, Wq, bq, Wv,
                     bih1, bhh1, bih2, bhh2, bih3, bhh3, hx1, hx2, hx3, wsb);
  hipLaunchKernelGGL(k_cvt, dim3(9376), dim3(256), 0, stream, key, val, Wq,
                     Wih1, Whh1, Wih2, Whh2, Wih3, Whh3, wsb);

  void* args[] = {(void*)&target, (void*)&tmask, (void*)&amask, (void*)&emb,
                  (void*)&bq,     (void*)&bv,    (void*)&cx1,   (void*)&cx2,
                  (void*)&cx3,    (void*)&wsb,   (void*)&out};
  hipLaunchCooperativeKernel((const void*)kmain, dim3(NWG), dim3(TPB), args, 0,
                             stream);
}

// Round 8
// 14952.669 us; speedup vs baseline: 1.9157x; 1.1850x over previous
//
#include <hip/hip_runtime.h>
#include <hip/hip_fp16.h>

// SpellerModel round 8: persistent cooperative kernel, 256 WGs x 512 thr.
// vs round 7: cross-WG DATA moves via plain sc0 sc1 loads/stores (L1+L2
// bypass -> LLC-coherent, read-only loads, no RMW write-back tax). Only the
// barrier + lossacc use atomic RMW. Explicit vmcnt(0) drain at barrier entry
// orders sc1 stores before the barrier's atomic arrival.

#define BB 64
#define TT 200
#define SS 400
#define VV 34
#define EE 256
#define HH 512
#define KD 256
#define NSTEP 201
#define NWG 256
#define TPB 512

typedef unsigned long long u64;

// ---- workspace byte offsets ----
#define OX1   0u            // halves [2][64][1024] (emb|ctx|h1)
#define OX2   262144u       // halves [2][64][1024] (h1|h2)
#define OX3   524288u       // halves [2][64][1024] (h2|h3)
#define OBS1  786432u       // f32 [2048] bih+bhh
#define OBS2  794624u
#define OBS3  802816u
#define OWVT  811008u       // f32 [512][34]
#define OLACC 880640u       // f32 [64]
#define OBAR  880896u       // u32 [1024] barrier + cnt8 + claim256
#define OW16  1048576u      // fp16 [3][2048][1024] (Wih|Whh per row)
#define OWQ   13631488u     // fp16 [256][512]
#define OKEY  13893632u     // fp16 [64][400][256]
#define OVAL  27000832u     // fp16 [64][400][256]

// ---------------- coherent access helpers ---------------------------------
// sc1 loads bypass the (non-XCD-coherent) L2 -> read LLC-latest. sc0 sc1
// stores write through to the LLC. X buffers are ONLY touched via these.
__device__ __forceinline__ void cload_x2_16(const void* p0, const void* p1,
                                            uint4& a, uint4& b) {
  asm volatile(
      "global_load_dwordx4 %0, %2, off sc0 sc1\n\t"
      "global_load_dwordx4 %1, %3, off sc0 sc1\n\t"
      "s_waitcnt vmcnt(0)"
      : "=&v"(a), "=&v"(b)
      : "v"(p0), "v"(p1)
      : "memory");
}
__device__ __forceinline__ u64 cload_u64(const void* p) {
  u64 v;
  asm volatile(
      "global_load_dwordx2 %0, %1, off sc0 sc1\n\t"
      "s_waitcnt vmcnt(0)"
      : "=&v"(v)
      : "v"(p)
      : "memory");
  return v;
}
__device__ __forceinline__ void cstore_u32(void* p, unsigned v) {
  asm volatile("global_store_dword %0, %1, off sc0 sc1" ::"v"(p), "v"(v)
               : "memory");
}
__device__ __forceinline__ void cstore_u64(void* p, u64 v) {
  asm volatile("global_store_dwordx2 %0, %1, off sc0 sc1" ::"v"(p), "v"(v)
               : "memory");
}
// atomic RMW (barrier / lossacc only)
__device__ __forceinline__ unsigned aload_u32(const unsigned* p) {
  unsigned v;
  asm volatile(
      "global_atomic_or %0, %1, %2, off sc0 sc1\n\t"
      "s_waitcnt vmcnt(0)"
      : "=&v"(v)
      : "v"(p), "v"(0u)
      : "memory");
  return v;
}
__device__ __forceinline__ void astore_u32(unsigned* p, unsigned v) {
  __hip_atomic_exchange(p, v, __ATOMIC_RELAXED, __HIP_MEMORY_SCOPE_AGENT);
}

// ---------------- fp16 pack / dot / nt helpers ----------------------------
__device__ __forceinline__ unsigned pack2h(float a, float b) {
  return (unsigned)__half_as_ushort(__float2half(a)) |
         ((unsigned)__half_as_ushort(__float2half(b)) << 16);
}
__device__ __forceinline__ u64 pack4h(float4 v) {
  return (u64)pack2h(v.x, v.y) | ((u64)pack2h(v.z, v.w) << 32);
}
__device__ __forceinline__ float dot2acc(unsigned x, unsigned w, float acc) {
#if __has_builtin(__builtin_amdgcn_fdot2)
  typedef _Float16 h2 __attribute__((ext_vector_type(2)));
  union C { unsigned u; h2 h; };
  C a, b;
  a.u = x;
  b.u = w;
  return __builtin_amdgcn_fdot2(a.h, b.h, acc, false);
#else
  const __half2 ha = *(const __half2*)&x, hb = *(const __half2*)&w;
  const float2 fa = __half22float2(ha), fb = __half22float2(hb);
  return fmaf(fa.y, fb.y, fmaf(fa.x, fb.x, acc));
#endif
}

// ---------------------------- LDS union -----------------------------------
struct __align__(16) SM {
  union {
    union {
      u64 xs[8 * 258];                               // x staged, pitch 258 u64
      struct { float red[256 * 17]; float gates[8 * 65]; } r;
    } l;
    struct {
      unsigned h3u[256];
      float qp[2][256];
      float qf[256];
      unsigned qh[128];
      float an[SS];
      float red[8];
      float cxp[4][256];
    } a;
    struct { float h3f[512]; float redl[VV * 8]; float lbuf[VV]; } g;
  };
};

// ------------------------- global barrier ---------------------------------
__device__ __forceinline__ void gbar(unsigned* bar, int wg) {
  asm volatile("s_waitcnt vmcnt(0)" ::: "memory");  // drain sc1 stores
  __syncthreads();
  if (threadIdx.x == 0) {
    unsigned* cnt = bar + (wg >> 5) * 16;
    unsigned* gen = bar + 128 + (wg >> 5) * 16;
    unsigned* rc = bar + 256;
    unsigned* rgen = bar + 272;
    const unsigned g0 = aload_u32(gen);
    if (__hip_atomic_fetch_add(cnt, 1u, __ATOMIC_RELAXED,
                               __HIP_MEMORY_SCOPE_AGENT) == 31u) {
      const unsigned r0 = aload_u32(rgen);
      if (__hip_atomic_fetch_add(rc, 1u, __ATOMIC_RELAXED,
                                 __HIP_MEMORY_SCOPE_AGENT) == 7u) {
        __hip_atomic_fetch_add(rc, (unsigned)-8, __ATOMIC_RELAXED,
                               __HIP_MEMORY_SCOPE_AGENT);
        __hip_atomic_fetch_add(rgen, 1u, __ATOMIC_RELAXED,
                               __HIP_MEMORY_SCOPE_AGENT);
      } else {
        while (aload_u32(rgen) == r0) __builtin_amdgcn_s_sleep(1);
      }
      __hip_atomic_fetch_add(cnt, (unsigned)-32, __ATOMIC_RELAXED,
                             __HIP_MEMORY_SCOPE_AGENT);
      __hip_atomic_fetch_add(gen, 1u, __ATOMIC_RELAXED,
                             __HIP_MEMORY_SCOPE_AGENT);
    } else {
      while (aload_u32(gen) == g0) __builtin_amdgcn_s_sleep(1);
    }
    asm volatile("" ::: "memory");
  }
  __syncthreads();
}

// ------------------------------- LSTM stage -------------------------------
// WG covers cgI (16 units, 64 gate rows) x 8 batches (b0..b0+7).
// Thread tid = ks*32 + rg*2 + bg: 4 rows x 4 batches, K-slice 64 halves.
// x from LDS (padded pitch, broadcast), W16 from XCD-local L2.
__device__ __forceinline__ void lstm_stage(SM& sm, int cgI, int b0,
                                           const u64* Xc,
                                           const unsigned short* W16,
                                           const float* __restrict__ bsum,
                                           float& creg, unsigned* d1, int o1,
                                           unsigned* d2, int o2) {
  const int tid = threadIdx.x;
  {  // stage x[b0..b0+7][0:1024] halves via sc1 loads into padded LDS
    const char* src = (const char*)(Xc + (size_t)b0 * 256);
    uint4 a, b;
    cload_x2_16(src + (size_t)tid * 16, src + 8192 + (size_t)tid * 16, a, b);
    const int i0 = 2 * tid, i1 = 2 * tid + 1024;
    *(uint4*)&sm.l.xs[(i0 >> 8) * 258 + (i0 & 255)] = a;
    *(uint4*)&sm.l.xs[(i1 >> 8) * 258 + (i1 & 255)] = b;
  }
  __syncthreads();
  const int g = tid & 31, ks = tid >> 5;
  const int rg = g >> 1, bg = g & 1;
  const int R0 = ((rg >> 2) << 9) + (cgI << 4) + ((rg & 3) << 2);
  const unsigned* wb = (const unsigned*)W16;
  const unsigned* wp0 = wb + (size_t)(R0 + 0) * 512 + ks * 32;
  const unsigned* wp1 = wb + (size_t)(R0 + 1) * 512 + ks * 32;
  const unsigned* wp2 = wb + (size_t)(R0 + 2) * 512 + ks * 32;
  const unsigned* wp3 = wb + (size_t)(R0 + 3) * 512 + ks * 32;
  const unsigned* xl = (const unsigned*)sm.l.xs;
  const int xbase = bg * 4 * 516 + ks * 32;
  float acc[4][4];
#pragma unroll
  for (int i = 0; i < 4; ++i)
#pragma unroll
    for (int j = 0; j < 4; ++j) acc[i][j] = 0.f;
#pragma unroll
  for (int kk = 0; kk < 8; ++kk) {
    uint4 wv[4], xv[4];
    wv[0] = *(const uint4*)&wp0[kk * 4];
    wv[1] = *(const uint4*)&wp1[kk * 4];
    wv[2] = *(const uint4*)&wp2[kk * 4];
    wv[3] = *(const uint4*)&wp3[kk * 4];
#pragma unroll
    for (int j = 0; j < 4; ++j)
      xv[j] = *(const uint4*)&xl[xbase + j * 516 + kk * 4];
#pragma unroll
    for (int i = 0; i < 4; ++i) {
#pragma unroll
      for (int j = 0; j < 4; ++j) {
        acc[i][j] = dot2acc(xv[j].x, wv[i].x, acc[i][j]);
        acc[i][j] = dot2acc(xv[j].y, wv[i].y, acc[i][j]);
        acc[i][j] = dot2acc(xv[j].z, wv[i].z, acc[i][j]);
        acc[i][j] = dot2acc(xv[j].w, wv[i].w, acc[i][j]);
      }
    }
  }
  __syncthreads();  // xs dead; red overlays
#pragma unroll
  for (int i = 0; i < 4; ++i)
#pragma unroll
    for (int j = 0; j < 4; ++j) acc[i][j] += __shfl_xor(acc[i][j], 32);
  if ((tid & 32) == 0) {
    const int wtid = (tid >> 6) * 32 + g;  // 0..255
#pragma unroll
    for (int i = 0; i < 4; ++i)
#pragma unroll
      for (int j = 0; j < 4; ++j)
        sm.l.r.red[wtid * 17 + i * 4 + j] = acc[i][j];
  }
  __syncthreads();
  {  // final: output o = r*8 + b, sum 8 kp-partials
    const int o = tid;
    const int org = o >> 5, oi = (o >> 3) & 3, obg = (o >> 2) & 1, oj = o & 3;
    const int gslot = org * 2 + obg, idx = oi * 4 + oj;
    float s = 0.f;
#pragma unroll
    for (int kp = 0; kp < 8; ++kp)
      s += sm.l.r.red[(kp * 32 + gslot) * 17 + idx];
    const int r = o >> 3, bl = o & 7;
    sm.l.r.gates[bl * 65 + r] = s;
  }
  __syncthreads();
  if (tid < 128) {
    const int bl = tid >> 4, uu = tid & 15;
    const int u = (cgI << 4) + uu;
    const float* gts = &sm.l.r.gates[bl * 65];
    const float gi = gts[uu] + bsum[u];
    const float gf = gts[16 + uu] + bsum[512 + u];
    const float gG = gts[32 + uu] + bsum[1024 + u];
    const float go = gts[48 + uu] + bsum[1536 + u];
    const float si = 1.f / (1.f + expf(-gi));
    const float sf = 1.f / (1.f + expf(-gf));
    const float so = 1.f / (1.f + expf(-go));
    const float cn = sf * creg + si * tanhf(gG);
    const float hn = so * tanhf(cn);
    creg = cn;
    const unsigned hb = (unsigned)__half_as_ushort(__float2half(hn));
    const unsigned ob = __shfl_down(hb, 1);
    if ((uu & 1) == 0) {
      const unsigned pk = hb | (ob << 16);
      const size_t off = (size_t)(b0 + bl) * 512 + (u >> 1);
      cstore_u32(d1 + off + o1, pk);
      if (d2) cstore_u32(d2 + off + o2, pk);
    }
  }
  __syncthreads();
}

// --------------------- attention (incl. its own q) ------------------------
__device__ __forceinline__ void attn_stage(
    SM& sm, int b, int t, const u64* X3n, const unsigned short* Wq16,
    const float* __restrict__ bq, const __half* __restrict__ key16,
    const __half* __restrict__ val16, const float* __restrict__ amask,
    unsigned* X1n32, float* __restrict__ dout) {
  const int tid = threadIdx.x;
  if (tid < 128) {
    const u64 v = cload_u64(X3n + (size_t)b * 256 + 128 + tid);
    *(u64*)&sm.a.h3u[(size_t)tid * 2] = v;
  }
  __syncthreads();
  {  // q = h3 @ Wq.T
    const int c = tid & 255, kh = tid >> 8;
    const unsigned* wq = (const unsigned*)Wq16 + (size_t)c * 256 + kh * 128;
    const unsigned* hp = &sm.a.h3u[kh * 128];
    float a = 0.f;
#pragma unroll 8
    for (int i = 0; i < 32; ++i) {
      const uint4 w4 = *(const uint4*)&wq[i * 4];
      const uint4 x4 = *(const uint4*)&hp[i * 4];
      a = dot2acc(x4.x, w4.x, a);
      a = dot2acc(x4.y, w4.y, a);
      a = dot2acc(x4.z, w4.z, a);
      a = dot2acc(x4.w, w4.w, a);
    }
    sm.a.qp[kh][c] = a;
  }
  __syncthreads();
  if (tid < 256) sm.a.qf[tid] = sm.a.qp[0][tid] + sm.a.qp[1][tid] + bq[tid];
  __syncthreads();
  if (tid < 128) sm.a.qh[tid] = pack2h(sm.a.qf[2 * tid], sm.a.qf[2 * tid + 1]);
  __syncthreads();
  float e = -1e30f;
  if (tid < SS) {
    const unsigned* kp = (const unsigned*)key16 + ((size_t)b * SS + tid) * 128;
    float a = 0.f;
#pragma unroll 8
    for (int i = 0; i < 32; ++i) {
      const uint4 k4 = *(const uint4*)&kp[i * 4];
      const uint4 q4 = *(const uint4*)&sm.a.qh[i * 4];
      a = dot2acc(q4.x, k4.x, a);
      a = dot2acc(q4.y, k4.y, a);
      a = dot2acc(q4.z, k4.z, a);
      a = dot2acc(q4.w, k4.w, a);
    }
    e = a;
  }
  float m = e;
  for (int o = 32; o; o >>= 1) m = fmaxf(m, __shfl_xor(m, o));
  if ((tid & 63) == 0) sm.a.red[tid >> 6] = m;
  __syncthreads();
  m = sm.a.red[0];
#pragma unroll
  for (int i = 1; i < 8; ++i) m = fmaxf(m, sm.a.red[i]);
  __syncthreads();
  const float p = (tid < SS) ? expf(e - m) : 0.f;
  float z = p;
  for (int o = 32; o; o >>= 1) z += __shfl_xor(z, o);
  if ((tid & 63) == 0) sm.a.red[tid >> 6] = z;
  __syncthreads();
  z = 0.f;
#pragma unroll
  for (int i = 0; i < 8; ++i) z += sm.a.red[i];
  __syncthreads();
  const float at = p / z;
  if (b == 0 && tid < SS) dout[1 + (size_t)t * SS + tid] = at;
  const float am = (tid < SS) ? at * amask[(size_t)b * SS + tid] : 0.f;
  float sa = fabsf(am);
  for (int o = 32; o; o >>= 1) sa += __shfl_xor(sa, o);
  if ((tid & 63) == 0) sm.a.red[tid >> 6] = sa;
  __syncthreads();
  sa = 0.f;
#pragma unroll
  for (int i = 0; i < 8; ++i) sa += sm.a.red[i];
  const float inv = 1.f / fmaxf(sa, 1e-12f);
  if (tid < SS) sm.a.an[tid] = am * inv;
  __syncthreads();
  {  // ctx: 128 k-pairs x 4 s-quarters, packed half2 nontemporal loads
    const int k2 = tid & 127, sq = tid >> 7;
    const __half* vp = val16 + ((size_t)b * SS + sq * 100) * 256 + k2 * 2;
    const float* ap = &sm.a.an[sq * 100];
    float a0 = 0.f, a1 = 0.f;
#pragma unroll 4
    for (int s = 0; s < 100; ++s) {
      const unsigned u =
          __builtin_nontemporal_load((const unsigned*)(vp + (size_t)s * 256));
      const float2 f = __half22float2(*(const __half2*)&u);
      a0 = fmaf(ap[s], f.x, a0);
      a1 = fmaf(ap[s], f.y, a1);
    }
    sm.a.cxp[sq][2 * k2] = a0;
    sm.a.cxp[sq][2 * k2 + 1] = a1;
  }
  __syncthreads();
  if (tid < 128) {
    const float v0 = sm.a.cxp[0][2 * tid] + sm.a.cxp[1][2 * tid] +
                     sm.a.cxp[2][2 * tid] + sm.a.cxp[3][2 * tid];
    const float v1 = sm.a.cxp[0][2 * tid + 1] + sm.a.cxp[1][2 * tid + 1] +
                     sm.a.cxp[2][2 * tid + 1] + sm.a.cxp[3][2 * tid + 1];
    cstore_u32(X1n32 + (size_t)b * 512 + 128 + tid, pack2h(v0, v1));
  }
  __syncthreads();
}

// ------------------------------ logits + nll ------------------------------
__device__ __forceinline__ void logits_stage(SM& sm, int b, int t,
                                             const u64* X3n,
                                             const float* __restrict__ WvT,
                                             const float* __restrict__ bv,
                                             const int* __restrict__ target,
                                             const float* __restrict__ tmask,
                                             float& lreg) {
  const int tid = threadIdx.x;
  if (tid < 128) {
    const u64 v = cload_u64(X3n + (size_t)b * 256 + 128 + tid);
    unsigned lo = (unsigned)v, hi = (unsigned)(v >> 32);
    const __half2 h0 = *(const __half2*)&lo, h1 = *(const __half2*)&hi;
    const float2 f0 = __half22float2(h0), f1 = __half22float2(h1);
    sm.g.h3f[tid * 4 + 0] = f0.x;
    sm.g.h3f[tid * 4 + 1] = f0.y;
    sm.g.h3f[tid * 4 + 2] = f1.x;
    sm.g.h3f[tid * 4 + 3] = f1.y;
  }
  __syncthreads();
  {
    const int c = tid & 63, ks = tid >> 6;
    if (c < VV) {
      float a = 0.f;
      const float* hp = &sm.g.h3f[ks * 64];
      const float* wp = WvT + (size_t)(ks * 64) * VV + c;
#pragma unroll 4
      for (int h = 0; h < 64; ++h) a = fmaf(hp[h], wp[h * VV], a);
      sm.g.redl[c * 8 + ks] = a;
    }
  }
  __syncthreads();
  if (tid < VV) {
    const float* rp = &sm.g.redl[tid * 8];
    float l = bv[tid];
#pragma unroll
    for (int k = 0; k < 8; ++k) l += rp[k];
    sm.g.lbuf[tid] = l;
  }
  __syncthreads();
  if (tid == 0) {
    float M = sm.g.lbuf[0];
    for (int v = 1; v < VV; ++v) M = fmaxf(M, sm.g.lbuf[v]);
    float Z = 0.f;
    for (int v = 0; v < VV; ++v) Z += expf(sm.g.lbuf[v] - M);
    const int yy = target[t * BB + b];
    lreg += tmask[t * BB + b] * (-(sm.g.lbuf[yy] - M - logf(Z)));
  }
  __syncthreads();
}

// --------------------------------- main -----------------------------------
__global__ void __launch_bounds__(TPB, 1) kmain(
    const int* __restrict__ target, const float* __restrict__ tmask,
    const float* __restrict__ amask, const float* __restrict__ emb,
    const float* __restrict__ bq, const float* __restrict__ bv,
    const float* __restrict__ cx1, const float* __restrict__ cx2,
    const float* __restrict__ cx3, char* wsb, float* __restrict__ dout) {
  __shared__ SM sm;
  __shared__ int s_wid;
  const int wg = blockIdx.x, tid = threadIdx.x;
  unsigned* bar = (unsigned*)(wsb + OBAR);
  const unsigned short* W1 = (const unsigned short*)(wsb + OW16);
  const unsigned short* W2 = W1 + 2097152;
  const unsigned short* W3 = W2 + 2097152;
  const unsigned short* Wq16 = (const unsigned short*)(wsb + OWQ);
  const __half* key16 = (const __half*)(wsb + OKEY);
  const __half* val16 = (const __half*)(wsb + OVAL);
  const float* bs1 = (const float*)(wsb + OBS1);
  const float* bs2 = (const float*)(wsb + OBS2);
  const float* bs3 = (const float*)(wsb + OBS3);
  const float* WvT = (const float*)(wsb + OWVT);
  float* lacc = (float*)(wsb + OLACC);

  // ---- XCD-affine workid claim (correct under any dispatch pattern) ----
  if (tid == 0) {
    unsigned xcc = 0;
    asm volatile("s_getreg_b32 %0, hwreg(20, 0, 32)" : "=s"(xcc));
    xcc &= 7u;
    unsigned* cnt = bar + 288;
    unsigned* claim = bar + 320;
    int wid = -1;
    const unsigned r = __hip_atomic_fetch_add(&cnt[xcc], 1u, __ATOMIC_RELAXED,
                                              __HIP_MEMORY_SCOPE_AGENT);
    if (r < 32u) {
      const int cand = (int)(xcc * 32u + r);
      if (__hip_atomic_exchange(&claim[cand], 1u, __ATOMIC_RELAXED,
                                __HIP_MEMORY_SCOPE_AGENT) == 0u)
        wid = cand;
    }
    for (int i = 0; wid < 0 && i < 256; ++i)
      if (__hip_atomic_exchange(&claim[i], 1u, __ATOMIC_RELAXED,
                                __HIP_MEMORY_SCOPE_AGENT) == 0u)
        wid = i;
    s_wid = wid;
  }
  __syncthreads();
  const int Wd = s_wid;
  const int xcls = Wd >> 5, lw = Wd & 31;
  const int cgI = xcls * 4 + (lw & 3);
  const int b0 = ((lw >> 2) & 7) * 8;

  float c1r = 0.f, c2r = 0.f, c3r = 0.f;
  if (tid < 128) {
    const int u = (cgI << 4) + (tid & 15);
    c1r = cx1[u];
    c2r = cx2[u];
    c3r = cx3[u];
  }
  float lreg = 0.f;

  for (int t = 0; t < NSTEP; ++t) {
    const int cur = t & 1, nxt = cur ^ 1;
    u64* X1c = (u64*)(wsb + OX1) + (size_t)cur * 16384;
    u64* X1n = (u64*)(wsb + OX1) + (size_t)nxt * 16384;
    u64* X2c = (u64*)(wsb + OX2) + (size_t)cur * 16384;
    u64* X2n = (u64*)(wsb + OX2) + (size_t)nxt * 16384;
    u64* X3c = (u64*)(wsb + OX3) + (size_t)cur * 16384;
    u64* X3n = (u64*)(wsb + OX3) + (size_t)nxt * 16384;

    lstm_stage(sm, cgI, b0, X1c, W1, bs1, c1r, (unsigned*)X2c, 0,
               (unsigned*)X1n, 256);
    gbar(bar, wg);
    lstm_stage(sm, cgI, b0, X2c, W2, bs2, c2r, (unsigned*)X3c, 0,
               (unsigned*)X2n, 256);
    gbar(bar, wg);
    lstm_stage(sm, cgI, b0, X3c, W3, bs3, c3r, (unsigned*)X3n, 256, nullptr,
               0);
    gbar(bar, wg);
    if (lw < 8) {
      attn_stage(sm, xcls * 8 + lw, t, X3n, Wq16, bq, key16, val16, amask,
                 (unsigned*)X1n, dout);
    } else if (lw < 16) {
      if (t < TT)
        logits_stage(sm, xcls * 8 + lw - 8, t, X3n, WvT, bv, target, tmask,
                     lreg);
    } else if (lw < 24) {
      const int b = xcls * 8 + lw - 16;
      if (t < TT && tid < 64) {
        const int y = target[t * BB + b];
        const float4 v = *(const float4*)&emb[(size_t)y * EE + tid * 4];
        cstore_u64(X1n + (size_t)b * 256 + tid, pack4h(v));
      }
    }
    gbar(bar, wg);
  }
  if (lw >= 8 && lw < 16 && tid == 0)
    astore_u32((unsigned*)&lacc[xcls * 8 + lw - 8], __float_as_uint(lreg));
  gbar(bar, wg);
  if (Wd == 0 && tid < 64) {
    float v = __uint_as_float(aload_u32((const unsigned*)&lacc[tid]));
    for (int o = 32; o; o >>= 1) v += __shfl_xor(v, o);
    if (tid == 0) dout[0] = v * (1.f / 64.f);
  }
}

// ---------------------------------- init ----------------------------------
__global__ void k_init(const float* emb, const float* Wq, const float* bq,
                       const float* Wv, const float* bih1, const float* bhh1,
                       const float* bih2, const float* bhh2, const float* bih3,
                       const float* bhh3, const float* hx1, const float* hx2,
                       const float* hx3, char* wsb) {
  const int b = blockIdx.x, tid = threadIdx.x;
  __half* X1 = (__half*)(wsb + OX1);
  __half* X2 = (__half*)(wsb + OX2);
  __half* X3 = (__half*)(wsb + OX3);
  __shared__ float hx[HH];
  for (int k = tid; k < HH; k += 256) {
    const float v = hx1[k];
    hx[k] = v;
    X1[b * 1024 + 512 + k] = __float2half(v);
    X2[b * 1024 + 512 + k] = __float2half(hx2[k]);
    X3[b * 1024 + 512 + k] = __float2half(hx3[k]);
  }
  for (int k = tid; k < EE; k += 256) X1[b * 1024 + k] = __float2half(emb[k]);
  __syncthreads();
  for (int c = tid; c < KD; c += 256) {
    float a = bq[c];
    for (int k = 0; k < HH; ++k) a = fmaf(hx[k], Wq[(size_t)c * HH + k], a);
    X1[b * 1024 + 256 + c] = __float2half(a);
  }
  if (b == 0) {
    float* s1 = (float*)(wsb + OBS1);
    float* s2 = (float*)(wsb + OBS2);
    float* s3 = (float*)(wsb + OBS3);
    for (int i = tid; i < 2048; i += 256) {
      s1[i] = bih1[i] + bhh1[i];
      s2[i] = bih2[i] + bhh2[i];
      s3[i] = bih3[i] + bhh3[i];
    }
    float* wvt = (float*)(wsb + OWVT);
    for (int i = tid; i < HH * VV; i += 256) {
      const int h = i / VV, v = i % VV;
      wvt[i] = Wv[(size_t)v * HH + h];
    }
    float* lacc = (float*)(wsb + OLACC);
    for (int i = tid; i < 64; i += 256) lacc[i] = 0.f;
    unsigned* bar = (unsigned*)(wsb + OBAR);
    for (int i = tid; i < 1024; i += 256) bar[i] = 0u;
  }
}

// ----------------------------- fp16 staging -------------------------------
__global__ void k_cvt(const float* key, const float* val, const float* Wq,
                      const float* Wih1, const float* Whh1, const float* Wih2,
                      const float* Whh2, const float* Wih3, const float* Whh3,
                      char* wsb) {
  const int blk = blockIdx.x, tid = threadIdx.x;
  if (blk < 6144) {  // W16: layer, row -> [Wih row | Whh row] fp16
    const int layer = blk >> 11, R = blk & 2047;
    const float* Wih = (layer == 0) ? Wih1 : ((layer == 1) ? Wih2 : Wih3);
    const float* Whh = (layer == 0) ? Whh1 : ((layer == 1) ? Whh2 : Whh3);
    __half* dst = (__half*)(wsb + OW16) + (size_t)layer * 2097152 +
                  (size_t)R * 1024;
    const int k0 = tid * 4;
    const float* src = (k0 < 512) ? &Wih[(size_t)R * 512 + k0]
                                  : &Whh[(size_t)R * 512 + (k0 - 512)];
    const float4 v = *(const float4*)src;
    dst[k0 + 0] = __float2half(v.x);
    dst[k0 + 1] = __float2half(v.y);
    dst[k0 + 2] = __float2half(v.z);
    dst[k0 + 3] = __float2half(v.w);
  } else if (blk < 7744) {  // key16 flat
    const size_t base = (size_t)(blk - 6144) * 4096 + (size_t)tid * 16;
    __half* dst = (__half*)(wsb + OKEY);
#pragma unroll
    for (int j = 0; j < 4; ++j) {
      const float4 v = *(const float4*)&key[base + j * 4];
      dst[base + j * 4 + 0] = __float2half(v.x);
      dst[base + j * 4 + 1] = __float2half(v.y);
      dst[base + j * 4 + 2] = __float2half(v.z);
      dst[base + j * 4 + 3] = __float2half(v.w);
    }
  } else if (blk < 9344) {  // val16 flat
    const size_t base = (size_t)(blk - 7744) * 4096 + (size_t)tid * 16;
    __half* dst = (__half*)(wsb + OVAL);
#pragma unroll
    for (int j = 0; j < 4; ++j) {
      const float4 v = *(const float4*)&val[base + j * 4];
      dst[base + j * 4 + 0] = __float2half(v.x);
      dst[base + j * 4 + 1] = __float2half(v.y);
      dst[base + j * 4 + 2] = __float2half(v.z);
      dst[base + j * 4 + 3] = __float2half(v.w);
    }
  } else {  // Wq16 flat [256][512]
    const size_t base = (size_t)(blk - 9344) * 4096 + (size_t)tid * 16;
    __half* dst = (__half*)(wsb + OWQ);
#pragma unroll
    for (int j = 0; j < 4; ++j) {
      const float4 v = *(const float4*)&Wq[base + j * 4];
      dst[base + j * 4 + 0] = __float2half(v.x);
      dst[base + j * 4 + 1] = __float2half(v.y);
      dst[base + j * 4 + 2] = __float2half(v.z);
      dst[base + j * 4 + 3] = __float2half(v.w);
    }
  }
}

// --------------------------------- launch ---------------------------------
extern "C" void kernel_launch(void* const* d_in, const int* in_sizes, int n_in,
                              void* d_out, int out_size, void* d_ws,
                              size_t ws_size, hipStream_t stream) {
  const int* target = (const int*)d_in[0];
  const float* tmask = (const float*)d_in[1];
  const float* key = (const float*)d_in[2];
  const float* val = (const float*)d_in[3];
  const float* amask = (const float*)d_in[4];
  const float* emb = (const float*)d_in[5];
  const float* Wih1 = (const float*)d_in[6];
  const float* Whh1 = (const float*)d_in[7];
  const float* bih1 = (const float*)d_in[8];
  const float* bhh1 = (const float*)d_in[9];
  const float* Wih2 = (const float*)d_in[10];
  const float* Whh2 = (const float*)d_in[11];
  const float* bih2 = (const float*)d_in[12];
  const float* bhh2 = (const float*)d_in[13];
  const float* Wih3 = (const float*)d_in[14];
  const float* Whh3 = (const float*)d_in[15];
  const float* bih3 = (const float*)d_in[16];
  const float* bhh3 = (const float*)d_in[17];
  const float* Wq = (const float*)d_in[18];
  const float* bq = (const float*)d_in[19];
  const float* Wv = (const float*)d_in[20];
  const float* bv = (const float*)d_in[21];
  const float* hx1 = (const float*)d_in[22];
  const float* cx1 = (const float*)d_in[23];
  const float* hx2 = (const float*)d_in[24];
  const float* cx2 = (const float*)d_in[25];
  const float* hx3 = (const float*)d_in[26];
  const float* cx3 = (const float*)d_in[27];
  float* out = (float*)d_out;
  char* wsb = (char*)d_ws;

  hipLaunchKernelGGL(k_init, dim3(64), dim3(256), 0, stream, emb, Wq, bq, Wv,
                     bih1, bhh1, bih2, bhh2, bih3, bhh3, hx1, hx2, hx3, wsb);
  hipLaunchKernelGGL(k_cvt, dim3(9376), dim3(256), 0, stream, key, val, Wq,
                     Wih1, Whh1, Wih2, Whh2, Wih3, Whh3, wsb);

  void* args[] = {(void*)&target, (void*)&tmask, (void*)&amask, (void*)&emb,
                  (void*)&bq,     (void*)&bv,    (void*)&cx1,   (void*)&cx2,
                  (void*)&cx3,    (void*)&wsb,   (void*)&out};
  hipLaunchCooperativeKernel((const void*)kmain, dim3(NWG), dim3(TPB), args, 0,
                             stream);
}

// Round 9
// 14579.672 us; speedup vs baseline: 1.9647x; 1.0256x over previous
//
#include <hip/hip_runtime.h>
#include <hip/hip_fp16.h>

// SpellerModel round 9: persistent cooperative kernel, 256 WGs x 512 thr.
// vs round 8: (1) barrier = monotonic-stamp flag array; arrival is one sc1
// store, exit is one global_load_dwordx4 poll over all 256 flags (no RMW,
// no line-ownership storms). (2) attention ctx loop: 8 s-slices x 64
// k-quads, 8B NT loads, unroll 5 (more loads in flight).

#define BB 64
#define TT 200
#define SS 400
#define VV 34
#define EE 256
#define HH 512
#define KD 256
#define NSTEP 201
#define NWG 256
#define TPB 512

typedef unsigned long long u64;

// ---- workspace byte offsets ----
#define OX1   0u            // halves [2][64][1024] (emb|ctx|h1)
#define OX2   262144u       // halves [2][64][1024] (h1|h2)
#define OX3   524288u       // halves [2][64][1024] (h2|h3)
#define OBS1  786432u       // f32 [2048] bih+bhh
#define OBS2  794624u
#define OBS3  802816u
#define OWVT  811008u       // f32 [512][34]
#define OLACC 880640u       // f32 [64]
#define OBAR  880896u       // u32 [1024]: flags[256] | cnt8@288 | claim@320
#define OW16  1048576u      // fp16 [3][2048][1024] (Wih|Whh per row)
#define OWQ   13631488u     // fp16 [256][512]
#define OKEY  13893632u     // fp16 [64][400][256]
#define OVAL  27000832u     // fp16 [64][400][256]

// ---------------- coherent access helpers ---------------------------------
__device__ __forceinline__ void cload_x2_16(const void* p0, const void* p1,
                                            uint4& a, uint4& b) {
  asm volatile(
      "global_load_dwordx4 %0, %2, off sc0 sc1\n\t"
      "global_load_dwordx4 %1, %3, off sc0 sc1\n\t"
      "s_waitcnt vmcnt(0)"
      : "=&v"(a), "=&v"(b)
      : "v"(p0), "v"(p1)
      : "memory");
}
__device__ __forceinline__ u64 cload_u64(const void* p) {
  u64 v;
  asm volatile(
      "global_load_dwordx2 %0, %1, off sc0 sc1\n\t"
      "s_waitcnt vmcnt(0)"
      : "=&v"(v)
      : "v"(p)
      : "memory");
  return v;
}
__device__ __forceinline__ uint4 cload_u128(const void* p) {
  uint4 v;
  asm volatile(
      "global_load_dwordx4 %0, %1, off sc0 sc1\n\t"
      "s_waitcnt vmcnt(0)"
      : "=&v"(v)
      : "v"(p)
      : "memory");
  return v;
}
__device__ __forceinline__ void cstore_u32(void* p, unsigned v) {
  asm volatile("global_store_dword %0, %1, off sc0 sc1" ::"v"(p), "v"(v)
               : "memory");
}
__device__ __forceinline__ void cstore_u64(void* p, u64 v) {
  asm volatile("global_store_dwordx2 %0, %1, off sc0 sc1" ::"v"(p), "v"(v)
               : "memory");
}
// atomic RMW (claim table / lossacc only)
__device__ __forceinline__ unsigned aload_u32(const unsigned* p) {
  unsigned v;
  asm volatile(
      "global_atomic_or %0, %1, %2, off sc0 sc1\n\t"
      "s_waitcnt vmcnt(0)"
      : "=&v"(v)
      : "v"(p), "v"(0u)
      : "memory");
  return v;
}
__device__ __forceinline__ void astore_u32(unsigned* p, unsigned v) {
  __hip_atomic_exchange(p, v, __ATOMIC_RELAXED, __HIP_MEMORY_SCOPE_AGENT);
}

// ---------------- fp16 pack / dot helpers ---------------------------------
__device__ __forceinline__ unsigned pack2h(float a, float b) {
  return (unsigned)__half_as_ushort(__float2half(a)) |
         ((unsigned)__half_as_ushort(__float2half(b)) << 16);
}
__device__ __forceinline__ u64 pack4h(float4 v) {
  return (u64)pack2h(v.x, v.y) | ((u64)pack2h(v.z, v.w) << 32);
}
__device__ __forceinline__ float dot2acc(unsigned x, unsigned w, float acc) {
#if __has_builtin(__builtin_amdgcn_fdot2)
  typedef _Float16 h2 __attribute__((ext_vector_type(2)));
  union C { unsigned u; h2 h; };
  C a, b;
  a.u = x;
  b.u = w;
  return __builtin_amdgcn_fdot2(a.h, b.h, acc, false);
#else
  const __half2 ha = *(const __half2*)&x, hb = *(const __half2*)&w;
  const float2 fa = __half22float2(ha), fb = __half22float2(hb);
  return fmaf(fa.y, fb.y, fmaf(fa.x, fb.x, acc));
#endif
}

// ---------------------------- LDS union -----------------------------------
struct __align__(16) SM {
  union {
    union {
      u64 xs[8 * 258];                               // x staged, pitch 258 u64
      struct { float red[256 * 17]; float gates[8 * 65]; } r;
    } l;
    struct {
      unsigned h3u[256];
      float qp[2][256];
      float qf[256];
      unsigned qh[128];
      float an[SS];
      float red[8];
      float cxp[8][256];
    } a;
    struct { float h3f[512]; float redl[VV * 8]; float lbuf[VV]; } g;
  };
};

// -------------------- flag barrier (no RMW, no contention) ----------------
// Arrival: tid0 stores monotonic stamp to flags[wg]. Exit: wave 0 polls all
// 256 flags with ONE dwordx4 (lane l -> flags[4l..4l+3]) until all >= stamp.
__device__ __forceinline__ void gbar(unsigned* flags, int wg, unsigned stamp) {
  asm volatile("s_waitcnt vmcnt(0)" ::: "memory");  // drain this thread's sc1 stores
  __syncthreads();
  const int tid = threadIdx.x;
  if (tid == 0) cstore_u32(flags + wg, stamp);
  if (tid < 64) {
    const unsigned* p = flags + 4 * tid;
    for (;;) {
      const uint4 v = cload_u128(p);
      const bool ok = (v.x >= stamp) & (v.y >= stamp) & (v.z >= stamp) &
                      (v.w >= stamp);
      if (__all(ok)) break;
      __builtin_amdgcn_s_sleep(2);
    }
  }
  __syncthreads();
}

// ------------------------------- LSTM stage -------------------------------
// WG covers cgI (16 units, 64 gate rows) x 8 batches (b0..b0+7).
// Thread tid = ks*32 + rg*2 + bg: 4 rows x 4 batches, K-slice 64 halves.
// x from LDS (padded pitch, broadcast), W16 from XCD-local L2.
__device__ __forceinline__ void lstm_stage(SM& sm, int cgI, int b0,
                                           const u64* Xc,
                                           const unsigned short* W16,
                                           const float* __restrict__ bsum,
                                           float& creg, unsigned* d1, int o1,
                                           unsigned* d2, int o2) {
  const int tid = threadIdx.x;
  {  // stage x[b0..b0+7][0:1024] halves via sc1 loads into padded LDS
    const char* src = (const char*)(Xc + (size_t)b0 * 256);
    uint4 a, b;
    cload_x2_16(src + (size_t)tid * 16, src + 8192 + (size_t)tid * 16, a, b);
    const int i0 = 2 * tid, i1 = 2 * tid + 1024;
    *(uint4*)&sm.l.xs[(i0 >> 8) * 258 + (i0 & 255)] = a;
    *(uint4*)&sm.l.xs[(i1 >> 8) * 258 + (i1 & 255)] = b;
  }
  __syncthreads();
  const int g = tid & 31, ks = tid >> 5;
  const int rg = g >> 1, bg = g & 1;
  const int R0 = ((rg >> 2) << 9) + (cgI << 4) + ((rg & 3) << 2);
  const unsigned* wb = (const unsigned*)W16;
  const unsigned* wp0 = wb + (size_t)(R0 + 0) * 512 + ks * 32;
  const unsigned* wp1 = wb + (size_t)(R0 + 1) * 512 + ks * 32;
  const unsigned* wp2 = wb + (size_t)(R0 + 2) * 512 + ks * 32;
  const unsigned* wp3 = wb + (size_t)(R0 + 3) * 512 + ks * 32;
  const unsigned* xl = (const unsigned*)sm.l.xs;
  const int xbase = bg * 4 * 516 + ks * 32;
  float acc[4][4];
#pragma unroll
  for (int i = 0; i < 4; ++i)
#pragma unroll
    for (int j = 0; j < 4; ++j) acc[i][j] = 0.f;
#pragma unroll
  for (int kk = 0; kk < 8; ++kk) {
    uint4 wv[4], xv[4];
    wv[0] = *(const uint4*)&wp0[kk * 4];
    wv[1] = *(const uint4*)&wp1[kk * 4];
    wv[2] = *(const uint4*)&wp2[kk * 4];
    wv[3] = *(const uint4*)&wp3[kk * 4];
#pragma unroll
    for (int j = 0; j < 4; ++j)
      xv[j] = *(const uint4*)&xl[xbase + j * 516 + kk * 4];
#pragma unroll
    for (int i = 0; i < 4; ++i) {
#pragma unroll
      for (int j = 0; j < 4; ++j) {
        acc[i][j] = dot2acc(xv[j].x, wv[i].x, acc[i][j]);
        acc[i][j] = dot2acc(xv[j].y, wv[i].y, acc[i][j]);
        acc[i][j] = dot2acc(xv[j].z, wv[i].z, acc[i][j]);
        acc[i][j] = dot2acc(xv[j].w, wv[i].w, acc[i][j]);
      }
    }
  }
  __syncthreads();  // xs dead; red overlays
#pragma unroll
  for (int i = 0; i < 4; ++i)
#pragma unroll
    for (int j = 0; j < 4; ++j) acc[i][j] += __shfl_xor(acc[i][j], 32);
  if ((tid & 32) == 0) {
    const int wtid = (tid >> 6) * 32 + g;  // 0..255
#pragma unroll
    for (int i = 0; i < 4; ++i)
#pragma unroll
      for (int j = 0; j < 4; ++j)
        sm.l.r.red[wtid * 17 + i * 4 + j] = acc[i][j];
  }
  __syncthreads();
  {  // final: output o = r*8 + b, sum 8 kp-partials
    const int o = tid;
    const int org = o >> 5, oi = (o >> 3) & 3, obg = (o >> 2) & 1, oj = o & 3;
    const int gslot = org * 2 + obg, idx = oi * 4 + oj;
    float s = 0.f;
#pragma unroll
    for (int kp = 0; kp < 8; ++kp)
      s += sm.l.r.red[(kp * 32 + gslot) * 17 + idx];
    const int r = o >> 3, bl = o & 7;
    sm.l.r.gates[bl * 65 + r] = s;
  }
  __syncthreads();
  if (tid < 128) {
    const int bl = tid >> 4, uu = tid & 15;
    const int u = (cgI << 4) + uu;
    const float* gts = &sm.l.r.gates[bl * 65];
    const float gi = gts[uu] + bsum[u];
    const float gf = gts[16 + uu] + bsum[512 + u];
    const float gG = gts[32 + uu] + bsum[1024 + u];
    const float go = gts[48 + uu] + bsum[1536 + u];
    const float si = 1.f / (1.f + expf(-gi));
    const float sf = 1.f / (1.f + expf(-gf));
    const float so = 1.f / (1.f + expf(-go));
    const float cn = sf * creg + si * tanhf(gG);
    const float hn = so * tanhf(cn);
    creg = cn;
    const unsigned hb = (unsigned)__half_as_ushort(__float2half(hn));
    const unsigned ob = __shfl_down(hb, 1);
    if ((uu & 1) == 0) {
      const unsigned pk = hb | (ob << 16);
      const size_t off = (size_t)(b0 + bl) * 512 + (u >> 1);
      cstore_u32(d1 + off + o1, pk);
      if (d2) cstore_u32(d2 + off + o2, pk);
    }
  }
  __syncthreads();
}

// --------------------- attention (incl. its own q) ------------------------
__device__ __forceinline__ void attn_stage(
    SM& sm, int b, int t, const u64* X3n, const unsigned short* Wq16,
    const float* __restrict__ bq, const __half* __restrict__ key16,
    const __half* __restrict__ val16, const float* __restrict__ amask,
    unsigned* X1n32, float* __restrict__ dout) {
  const int tid = threadIdx.x;
  if (tid < 128) {
    const u64 v = cload_u64(X3n + (size_t)b * 256 + 128 + tid);
    *(u64*)&sm.a.h3u[(size_t)tid * 2] = v;
  }
  __syncthreads();
  {  // q = h3 @ Wq.T
    const int c = tid & 255, kh = tid >> 8;
    const unsigned* wq = (const unsigned*)Wq16 + (size_t)c * 256 + kh * 128;
    const unsigned* hp = &sm.a.h3u[kh * 128];
    float a = 0.f;
#pragma unroll 8
    for (int i = 0; i < 32; ++i) {
      const uint4 w4 = *(const uint4*)&wq[i * 4];
      const uint4 x4 = *(const uint4*)&hp[i * 4];
      a = dot2acc(x4.x, w4.x, a);
      a = dot2acc(x4.y, w4.y, a);
      a = dot2acc(x4.z, w4.z, a);
      a = dot2acc(x4.w, w4.w, a);
    }
    sm.a.qp[kh][c] = a;
  }
  __syncthreads();
  if (tid < 256) sm.a.qf[tid] = sm.a.qp[0][tid] + sm.a.qp[1][tid] + bq[tid];
  __syncthreads();
  if (tid < 128) sm.a.qh[tid] = pack2h(sm.a.qf[2 * tid], sm.a.qf[2 * tid + 1]);
  __syncthreads();
  float e = -1e30f;
  if (tid < SS) {
    const unsigned* kp = (const unsigned*)key16 + ((size_t)b * SS + tid) * 128;
    float a = 0.f;
#pragma unroll 8
    for (int i = 0; i < 32; ++i) {
      const uint4 k4 = *(const uint4*)&kp[i * 4];
      const uint4 q4 = *(const uint4*)&sm.a.qh[i * 4];
      a = dot2acc(q4.x, k4.x, a);
      a = dot2acc(q4.y, k4.y, a);
      a = dot2acc(q4.z, k4.z, a);
      a = dot2acc(q4.w, k4.w, a);
    }
    e = a;
  }
  float m = e;
  for (int o = 32; o; o >>= 1) m = fmaxf(m, __shfl_xor(m, o));
  if ((tid & 63) == 0) sm.a.red[tid >> 6] = m;
  __syncthreads();
  m = sm.a.red[0];
#pragma unroll
  for (int i = 1; i < 8; ++i) m = fmaxf(m, sm.a.red[i]);
  __syncthreads();
  const float p = (tid < SS) ? expf(e - m) : 0.f;
  float z = p;
  for (int o = 32; o; o >>= 1) z += __shfl_xor(z, o);
  if ((tid & 63) == 0) sm.a.red[tid >> 6] = z;
  __syncthreads();
  z = 0.f;
#pragma unroll
  for (int i = 0; i < 8; ++i) z += sm.a.red[i];
  __syncthreads();
  const float at = p / z;
  if (b == 0 && tid < SS) dout[1 + (size_t)t * SS + tid] = at;
  const float am = (tid < SS) ? at * amask[(size_t)b * SS + tid] : 0.f;
  float sa = fabsf(am);
  for (int o = 32; o; o >>= 1) sa += __shfl_xor(sa, o);
  if ((tid & 63) == 0) sm.a.red[tid >> 6] = sa;
  __syncthreads();
  sa = 0.f;
#pragma unroll
  for (int i = 0; i < 8; ++i) sa += sm.a.red[i];
  const float inv = 1.f / fmaxf(sa, 1e-12f);
  if (tid < SS) sm.a.an[tid] = am * inv;
  __syncthreads();
  {  // ctx: 64 k-quads x 8 s-slices, 8B NT loads, deep unroll for ILP
    const int kq = tid & 63, sq = tid >> 6;
    const __half* vp = val16 + ((size_t)b * SS + sq * 50) * 256 + kq * 4;
    const float* ap = &sm.a.an[sq * 50];
    float a0 = 0.f, a1 = 0.f, a2 = 0.f, a3 = 0.f;
#pragma unroll 5
    for (int s = 0; s < 50; ++s) {
      const u64 u =
          __builtin_nontemporal_load((const u64*)(vp + (size_t)s * 256));
      const unsigned lo = (unsigned)u, hi = (unsigned)(u >> 32);
      const float2 f0 = __half22float2(*(const __half2*)&lo);
      const float2 f1 = __half22float2(*(const __half2*)&hi);
      const float w = ap[s];
      a0 = fmaf(w, f0.x, a0);
      a1 = fmaf(w, f0.y, a1);
      a2 = fmaf(w, f1.x, a2);
      a3 = fmaf(w, f1.y, a3);
    }
    float* cx = &sm.a.cxp[sq][kq * 4];
    cx[0] = a0;
    cx[1] = a1;
    cx[2] = a2;
    cx[3] = a3;
  }
  __syncthreads();
  if (tid < 128) {
    float v0 = 0.f, v1 = 0.f;
#pragma unroll
    for (int i = 0; i < 8; ++i) {
      v0 += sm.a.cxp[i][2 * tid];
      v1 += sm.a.cxp[i][2 * tid + 1];
    }
    cstore_u32(X1n32 + (size_t)b * 512 + 128 + tid, pack2h(v0, v1));
  }
  __syncthreads();
}

// ------------------------------ logits + nll ------------------------------
__device__ __forceinline__ void logits_stage(SM& sm, int b, int t,
                                             const u64* X3n,
                                             const float* __restrict__ WvT,
                                             const float* __restrict__ bv,
                                             const int* __restrict__ target,
                                             const float* __restrict__ tmask,
                                             float& lreg) {
  const int tid = threadIdx.x;
  if (tid < 128) {
    const u64 v = cload_u64(X3n + (size_t)b * 256 + 128 + tid);
    unsigned lo = (unsigned)v, hi = (unsigned)(v >> 32);
    const __half2 h0 = *(const __half2*)&lo, h1 = *(const __half2*)&hi;
    const float2 f0 = __half22float2(h0), f1 = __half22float2(h1);
    sm.g.h3f[tid * 4 + 0] = f0.x;
    sm.g.h3f[tid * 4 + 1] = f0.y;
    sm.g.h3f[tid * 4 + 2] = f1.x;
    sm.g.h3f[tid * 4 + 3] = f1.y;
  }
  __syncthreads();
  {
    const int c = tid & 63, ks = tid >> 6;
    if (c < VV) {
      float a = 0.f;
      const float* hp = &sm.g.h3f[ks * 64];
      const float* wp = WvT + (size_t)(ks * 64) * VV + c;
#pragma unroll 4
      for (int h = 0; h < 64; ++h) a = fmaf(hp[h], wp[h * VV], a);
      sm.g.redl[c * 8 + ks] = a;
    }
  }
  __syncthreads();
  if (tid < VV) {
    const float* rp = &sm.g.redl[tid * 8];
    float l = bv[tid];
#pragma unroll
    for (int k = 0; k < 8; ++k) l += rp[k];
    sm.g.lbuf[tid] = l;
  }
  __syncthreads();
  if (tid == 0) {
    float M = sm.g.lbuf[0];
    for (int v = 1; v < VV; ++v) M = fmaxf(M, sm.g.lbuf[v]);
    float Z = 0.f;
    for (int v = 0; v < VV; ++v) Z += expf(sm.g.lbuf[v] - M);
    const int yy = target[t * BB + b];
    lreg += tmask[t * BB + b] * (-(sm.g.lbuf[yy] - M - logf(Z)));
  }
  __syncthreads();
}

// --------------------------------- main -----------------------------------
__global__ void __launch_bounds__(TPB, 1) kmain(
    const int* __restrict__ target, const float* __restrict__ tmask,
    const float* __restrict__ amask, const float* __restrict__ emb,
    const float* __restrict__ bq, const float* __restrict__ bv,
    const float* __restrict__ cx1, const float* __restrict__ cx2,
    const float* __restrict__ cx3, char* wsb, float* __restrict__ dout) {
  __shared__ SM sm;
  __shared__ int s_wid;
  const int wg = blockIdx.x, tid = threadIdx.x;
  unsigned* bar = (unsigned*)(wsb + OBAR);
  unsigned* flags = bar;  // [256]
  const unsigned short* W1 = (const unsigned short*)(wsb + OW16);
  const unsigned short* W2 = W1 + 2097152;
  const unsigned short* W3 = W2 + 2097152;
  const unsigned short* Wq16 = (const unsigned short*)(wsb + OWQ);
  const __half* key16 = (const __half*)(wsb + OKEY);
  const __half* val16 = (const __half*)(wsb + OVAL);
  const float* bs1 = (const float*)(wsb + OBS1);
  const float* bs2 = (const float*)(wsb + OBS2);
  const float* bs3 = (const float*)(wsb + OBS3);
  const float* WvT = (const float*)(wsb + OWVT);
  float* lacc = (float*)(wsb + OLACC);

  // ---- XCD-affine workid claim (correct under any dispatch pattern) ----
  if (tid == 0) {
    unsigned xcc = 0;
    asm volatile("s_getreg_b32 %0, hwreg(20, 0, 32)" : "=s"(xcc));
    xcc &= 7u;
    unsigned* cnt = bar + 288;
    unsigned* claim = bar + 320;
    int wid = -1;
    const unsigned r = __hip_atomic_fetch_add(&cnt[xcc], 1u, __ATOMIC_RELAXED,
                                              __HIP_MEMORY_SCOPE_AGENT);
    if (r < 32u) {
      const int cand = (int)(xcc * 32u + r);
      if (__hip_atomic_exchange(&claim[cand], 1u, __ATOMIC_RELAXED,
                                __HIP_MEMORY_SCOPE_AGENT) == 0u)
        wid = cand;
    }
    for (int i = 0; wid < 0 && i < 256; ++i)
      if (__hip_atomic_exchange(&claim[i], 1u, __ATOMIC_RELAXED,
                                __HIP_MEMORY_SCOPE_AGENT) == 0u)
        wid = i;
    s_wid = wid;
  }
  __syncthreads();
  const int Wd = s_wid;
  const int xcls = Wd >> 5, lw = Wd & 31;
  const int cgI = xcls * 4 + (lw & 3);
  const int b0 = ((lw >> 2) & 7) * 8;

  float c1r = 0.f, c2r = 0.f, c3r = 0.f;
  if (tid < 128) {
    const int u = (cgI << 4) + (tid & 15);
    c1r = cx1[u];
    c2r = cx2[u];
    c3r = cx3[u];
  }
  float lreg = 0.f;
  unsigned bst = 1;

  for (int t = 0; t < NSTEP; ++t) {
    const int cur = t & 1, nxt = cur ^ 1;
    u64* X1c = (u64*)(wsb + OX1) + (size_t)cur * 16384;
    u64* X1n = (u64*)(wsb + OX1) + (size_t)nxt * 16384;
    u64* X2c = (u64*)(wsb + OX2) + (size_t)cur * 16384;
    u64* X2n = (u64*)(wsb + OX2) + (size_t)nxt * 16384;
    u64* X3c = (u64*)(wsb + OX3) + (size_t)cur * 16384;
    u64* X3n = (u64*)(wsb + OX3) + (size_t)nxt * 16384;

    lstm_stage(sm, cgI, b0, X1c, W1, bs1, c1r, (unsigned*)X2c, 0,
               (unsigned*)X1n, 256);
    gbar(flags, wg, bst++);
    lstm_stage(sm, cgI, b0, X2c, W2, bs2, c2r, (unsigned*)X3c, 0,
               (unsigned*)X2n, 256);
    gbar(flags, wg, bst++);
    lstm_stage(sm, cgI, b0, X3c, W3, bs3, c3r, (unsigned*)X3n, 256, nullptr,
               0);
    gbar(flags, wg, bst++);
    if (lw < 8) {
      attn_stage(sm, xcls * 8 + lw, t, X3n, Wq16, bq, key16, val16, amask,
                 (unsigned*)X1n, dout);
    } else if (lw < 16) {
      if (t < TT)
        logits_stage(sm, xcls * 8 + lw - 8, t, X3n, WvT, bv, target, tmask,
                     lreg);
    } else if (lw < 24) {
      const int b = xcls * 8 + lw - 16;
      if (t < TT && tid < 64) {
        const int y = target[t * BB + b];
        const float4 v = *(const float4*)&emb[(size_t)y * EE + tid * 4];
        cstore_u64(X1n + (size_t)b * 256 + tid, pack4h(v));
      }
    }
    gbar(flags, wg, bst++);
  }
  if (lw >= 8 && lw < 16 && tid == 0)
    astore_u32((unsigned*)&lacc[xcls * 8 + lw - 8], __float_as_uint(lreg));
  gbar(flags, wg, bst++);
  if (Wd == 0 && tid < 64) {
    float v = __uint_as_float(aload_u32((const unsigned*)&lacc[tid]));
    for (int o = 32; o; o >>= 1) v += __shfl_xor(v, o);
    if (tid == 0) dout[0] = v * (1.f / 64.f);
  }
}

// ---------------------------------- init ----------------------------------
__global__ void k_init(const float* emb, const float* Wq, const float* bq,
                       const float* Wv, const float* bih1, const float* bhh1,
                       const float* bih2, const float* bhh2, const float* bih3,
                       const float* bhh3, const float* hx1, const float* hx2,
                       const float* hx3, char* wsb) {
  const int b = blockIdx.x, tid = threadIdx.x;
  __half* X1 = (__half*)(wsb + OX1);
  __half* X2 = (__half*)(wsb + OX2);
  __half* X3 = (__half*)(wsb + OX3);
  __shared__ float hx[HH];
  for (int k = tid; k < HH; k += 256) {
    const float v = hx1[k];
    hx[k] = v;
    X1[b * 1024 + 512 + k] = __float2half(v);
    X2[b * 1024 + 512 + k] = __float2half(hx2[k]);
    X3[b * 1024 + 512 + k] = __float2half(hx3[k]);
  }
  for (int k = tid; k < EE; k += 256) X1[b * 1024 + k] = __float2half(emb[k]);
  __syncthreads();
  for (int c = tid; c < KD; c += 256) {
    float a = bq[c];
    for (int k = 0; k < HH; ++k) a = fmaf(hx[k], Wq[(size_t)c * HH + k], a);
    X1[b * 1024 + 256 + c] = __float2half(a);
  }
  if (b == 0) {
    float* s1 = (float*)(wsb + OBS1);
    float* s2 = (float*)(wsb + OBS2);
    float* s3 = (float*)(wsb + OBS3);
    for (int i = tid; i < 2048; i += 256) {
      s1[i] = bih1[i] + bhh1[i];
      s2[i] = bih2[i] + bhh2[i];
      s3[i] = bih3[i] + bhh3[i];
    }
    float* wvt = (float*)(wsb + OWVT);
    for (int i = tid; i < HH * VV; i += 256) {
      const int h = i / VV, v = i % VV;
      wvt[i] = Wv[(size_t)v * HH + h];
    }
    float* lacc = (float*)(wsb + OLACC);
    for (int i = tid; i < 64; i += 256) lacc[i] = 0.f;
    unsigned* bar = (unsigned*)(wsb + OBAR);
    for (int i = tid; i < 1024; i += 256) bar[i] = 0u;
  }
}

// ----------------------------- fp16 staging -------------------------------
__global__ void k_cvt(const float* key, const float* val, const float* Wq,
                      const float* Wih1, const float* Whh1, const float* Wih2,
                      const float* Whh2, const float* Wih3, const float* Whh3,
                      char* wsb) {
  const int blk = blockIdx.x, tid = threadIdx.x;
  if (blk < 6144) {  // W16: layer, row -> [Wih row | Whh row] fp16
    const int layer = blk >> 11, R = blk & 2047;
    const float* Wih = (layer == 0) ? Wih1 : ((layer == 1) ? Wih2 : Wih3);
    const float* Whh = (layer == 0) ? Whh1 : ((layer == 1) ? Whh2 : Whh3);
    __half* dst = (__half*)(wsb + OW16) + (size_t)layer * 2097152 +
                  (size_t)R * 1024;
    const int k0 = tid * 4;
    const float* src = (k0 < 512) ? &Wih[(size_t)R * 512 + k0]
                                  : &Whh[(size_t)R * 512 + (k0 - 512)];
    const float4 v = *(const float4*)src;
    dst[k0 + 0] = __float2half(v.x);
    dst[k0 + 1] = __float2half(v.y);
    dst[k0 + 2] = __float2half(v.z);
    dst[k0 + 3] = __float2half(v.w);
  } else if (blk < 7744) {  // key16 flat
    const size_t base = (size_t)(blk - 6144) * 4096 + (size_t)tid * 16;
    __half* dst = (__half*)(wsb + OKEY);
#pragma unroll
    for (int j = 0; j < 4; ++j) {
      const float4 v = *(const float4*)&key[base + j * 4];
      dst[base + j * 4 + 0] = __float2half(v.x);
      dst[base + j * 4 + 1] = __float2half(v.y);
      dst[base + j * 4 + 2] = __float2half(v.z);
      dst[base + j * 4 + 3] = __float2half(v.w);
    }
  } else if (blk < 9344) {  // val16 flat
    const size_t base = (size_t)(blk - 7744) * 4096 + (size_t)tid * 16;
    __half* dst = (__half*)(wsb + OVAL);
#pragma unroll
    for (int j = 0; j < 4; ++j) {
      const float4 v = *(const float4*)&val[base + j * 4];
      dst[base + j * 4 + 0] = __float2half(v.x);
      dst[base + j * 4 + 1] = __float2half(v.y);
      dst[base + j * 4 + 2] = __float2half(v.z);
      dst[base + j * 4 + 3] = __float2half(v.w);
    }
  } else {  // Wq16 flat [256][512]
    const size_t base = (size_t)(blk - 9344) * 4096 + (size_t)tid * 16;
    __half* dst = (__half*)(wsb + OWQ);
#pragma unroll
    for (int j = 0; j < 4; ++j) {
      const float4 v = *(const float4*)&Wq[base + j * 4];
      dst[base + j * 4 + 0] = __float2half(v.x);
      dst[base + j * 4 + 1] = __float2half(v.y);
      dst[base + j * 4 + 2] = __float2half(v.z);
      dst[base + j * 4 + 3] = __float2half(v.w);
    }
  }
}

// --------------------------------- launch ---------------------------------
extern "C" void kernel_launch(void* const* d_in, const int* in_sizes, int n_in,
                              void* d_out, int out_size, void* d_ws,
                              size_t ws_size, hipStream_t stream) {
  const int* target = (const int*)d_in[0];
  const float* tmask = (const float*)d_in[1];
  const float* key = (const float*)d_in[2];
  const float* val = (const float*)d_in[3];
  const float* amask = (const float*)d_in[4];
  const float* emb = (const float*)d_in[5];
  const float* Wih1 = (const float*)d_in[6];
  const float* Whh1 = (const float*)d_in[7];
  const float* bih1 = (const float*)d_in[8];
  const float* bhh1 = (const float*)d_in[9];
  const float* Wih2 = (const float*)d_in[10];
  const float* Whh2 = (const float*)d_in[11];
  const float* bih2 = (const float*)d_in[12];
  const float* bhh2 = (const float*)d_in[13];
  const float* Wih3 = (const float*)d_in[14];
  const float* Whh3 = (const float*)d_in[15];
  const float* bih3 = (const float*)d_in[16];
  const float* bhh3 = (const float*)d_in[17];
  const float* Wq = (const float*)d_in[18];
  const float* bq = (const float*)d_in[19];
  const float* Wv = (const float*)d_in[20];
  const float* bv = (const float*)d_in[21];
  const float* hx1 = (const float*)d_in[22];
  const float* cx1 = (const float*)d_in[23];
  const float* hx2 = (const float*)d_in[24];
  const float* cx2 = (const float*)d_in[25];
  const float* hx3 = (const float*)d_in[26];
  const float* cx3 = (const float*)d_in[27];
  float* out = (float*)d_out;
  char* wsb = (char*)d_ws;

  hipLaunchKernelGGL(k_init, dim3(64), dim3(256), 0, stream, emb, Wq, bq, Wv,
                     bih1, bhh1, bih2, bhh2, bih3, bhh3, hx1, hx2, hx3, wsb);
  hipLaunchKernelGGL(k_cvt, dim3(9376), dim3(256), 0, stream, key, val, Wq,
                     Wih1, Whh1, Wih2, Whh2, Wih3, Whh3, wsb);

  void* args[] = {(void*)&target, (void*)&tmask, (void*)&amask, (void*)&emb,
                  (void*)&bq,     (void*)&bv,    (void*)&cx1,   (void*)&cx2,
                  (void*)&cx3,    (void*)&wsb,   (void*)&out};
  hipLaunchCooperativeKernel((const void*)kmain, dim3(NWG), dim3(TPB), args, 0,
                             stream);
}

// Round 13
// 10041.676 us; speedup vs baseline: 2.8525x; 1.4519x over previous
//
#include <hip/hip_runtime.h>
#include <hip/hip_fp16.h>

// SpellerModel round 13: round 12 with asm-input fix (ext_vector uv4 for
// global_store_dwordx4 input operand). Hierarchical epoch barrier + 16B
// cross-WG accesses; compute identical to round 9.

#define BB 64
#define TT 200
#define SS 400
#define VV 34
#define EE 256
#define HH 512
#define KD 256
#define NSTEP 201
#define NWG 256
#define TPB 512

typedef unsigned long long u64;
typedef unsigned uv4 __attribute__((ext_vector_type(4)));

// ---- workspace byte offsets ----
#define OX1   0u            // halves [2][64][1024] (emb|ctx|h1)
#define OX2   262144u       // halves [2][64][1024] (h1|h2)
#define OX3   524288u       // halves [2][64][1024] (h2|h3)
#define OBS1  786432u       // f32 [2048] bih+bhh
#define OBS2  794624u
#define OBS3  802816u
#define OWVT  811008u       // f32 [512][34]
#define OLACC 880640u       // f32 [64]
#define OBAR  880896u       // u32 [1024]: flags[256] | epoch@260 | cnt8@288 | claim@320
#define OW16  1048576u      // fp16 [3][2048][1024] (Wih|Whh per row)
#define OWQ   13631488u     // fp16 [256][512]
#define OKEY  13893632u     // fp16 [64][400][256]
#define OVAL  27000832u     // fp16 [64][400][256]

// ---------------- coherent access helpers ---------------------------------
__device__ __forceinline__ void cload_x2_16(const void* p0, const void* p1,
                                            uv4& a, uv4& b) {
  asm volatile(
      "global_load_dwordx4 %0, %2, off sc0 sc1\n\t"
      "global_load_dwordx4 %1, %3, off sc0 sc1\n\t"
      "s_waitcnt vmcnt(0)"
      : "=&v"(a), "=&v"(b)
      : "v"(p0), "v"(p1)
      : "memory");
}
__device__ __forceinline__ unsigned cload_u32g(const unsigned* p) {
  unsigned v;
  asm volatile(
      "global_load_dword %0, %1, off sc0 sc1\n\t"
      "s_waitcnt vmcnt(0)"
      : "=&v"(v)
      : "v"(p)
      : "memory");
  return v;
}
__device__ __forceinline__ uv4 cload_u128(const void* p) {
  uv4 v;
  asm volatile(
      "global_load_dwordx4 %0, %1, off sc0 sc1\n\t"
      "s_waitcnt vmcnt(0)"
      : "=&v"(v)
      : "v"(p)
      : "memory");
  return v;
}
__device__ __forceinline__ void cstore_u32(void* p, unsigned v) {
  asm volatile("global_store_dword %0, %1, off sc0 sc1" ::"v"(p), "v"(v)
               : "memory");
}
__device__ __forceinline__ void cstore_u128(void* p, uv4 v) {
  asm volatile("global_store_dwordx4 %0, %1, off sc0 sc1" ::"v"(p), "v"(v)
               : "memory");
}
// atomic RMW (claim table / lossacc only)
__device__ __forceinline__ unsigned aload_u32(const unsigned* p) {
  unsigned v;
  asm volatile(
      "global_atomic_or %0, %1, %2, off sc0 sc1\n\t"
      "s_waitcnt vmcnt(0)"
      : "=&v"(v)
      : "v"(p), "v"(0u)
      : "memory");
  return v;
}
__device__ __forceinline__ void astore_u32(unsigned* p, unsigned v) {
  __hip_atomic_exchange(p, v, __ATOMIC_RELAXED, __HIP_MEMORY_SCOPE_AGENT);
}

// ---------------- fp16 pack / dot helpers ---------------------------------
__device__ __forceinline__ unsigned pack2h(float a, float b) {
  return (unsigned)__half_as_ushort(__float2half(a)) |
         ((unsigned)__half_as_ushort(__float2half(b)) << 16);
}
__device__ __forceinline__ u64 pack4h(float4 v) {
  return (u64)pack2h(v.x, v.y) | ((u64)pack2h(v.z, v.w) << 32);
}
__device__ __forceinline__ float dot2acc(unsigned x, unsigned w, float acc) {
#if __has_builtin(__builtin_amdgcn_fdot2)
  typedef _Float16 h2 __attribute__((ext_vector_type(2)));
  union C { unsigned u; h2 h; };
  C a, b;
  a.u = x;
  b.u = w;
  return __builtin_amdgcn_fdot2(a.h, b.h, acc, false);
#else
  const __half2 ha = *(const __half2*)&x, hb = *(const __half2*)&w;
  const float2 fa = __half22float2(ha), fb = __half22float2(hb);
  return fmaf(fa.y, fb.y, fmaf(fa.x, fb.x, acc));
#endif
}

// ---------------------------- LDS union -----------------------------------
struct __align__(16) SM {
  union {
    union {
      u64 xs[8 * 258];                               // x staged, pitch 258 u64
      struct { float red[256 * 17]; float gates[8 * 65]; } r;
    } l;
    struct {
      unsigned h3u[256];
      float qp[2][256];
      float qf[256];
      unsigned qh[128];
      float an[SS];
      float red[8];
      float cxp[8][256];
    } a;
    struct { float h3f[512]; float redl[VV * 8]; float lbuf[VV]; } g;
  };
  __align__(16) unsigned short hl[8][16];  // h gather (outside union!)
};

// ------------- hierarchical flag barrier (epoch publish) ------------------
__device__ __forceinline__ void gbar(unsigned* flags, unsigned* epoch, int wg,
                                     unsigned stamp) {
  asm volatile("s_waitcnt vmcnt(0)" ::: "memory");  // drain sc1 stores
  __syncthreads();
  const int tid = threadIdx.x;
  if (tid == 0) cstore_u32(flags + wg, stamp);
  if (wg == 0) {
    if (tid < 64) {
      const unsigned* p = flags + 4 * tid;
      for (;;) {
        const uv4 v = cload_u128(p);
        const bool ok = (v.x >= stamp) & (v.y >= stamp) & (v.z >= stamp) &
                        (v.w >= stamp);
        if (__all(ok)) break;
        __builtin_amdgcn_s_sleep(1);
      }
    }
    __syncthreads();
    if (tid == 0) cstore_u32(epoch, stamp);
  } else {
    if (tid == 0) {
      while (cload_u32g(epoch) < stamp) __builtin_amdgcn_s_sleep(4);
    }
  }
  __syncthreads();
}

// ------------------------------- LSTM stage -------------------------------
// WG covers cgI (16 units, 64 gate rows) x 8 batches (b0..b0+7).
// Thread tid = ks*32 + rg*2 + bg: 4 rows x 4 batches, K-slice 64 halves.
// x from LDS (padded pitch, broadcast), W16 from XCD-local L2.
__device__ __forceinline__ void lstm_stage(SM& sm, int cgI, int b0,
                                           const char* Xc,
                                           const unsigned short* W16,
                                           const float* __restrict__ bsum,
                                           float& creg, char* d1, int o1,
                                           char* d2, int o2) {
  const int tid = threadIdx.x;
  {  // stage x[b0..b0+7][0:1024] halves via sc1 loads into padded LDS
    const char* src = Xc + (size_t)b0 * 2048;
    uv4 a, b;
    cload_x2_16(src + (size_t)tid * 16, src + 8192 + (size_t)tid * 16, a, b);
    const int i0 = 2 * tid, i1 = 2 * tid + 1024;
    *(uv4*)&sm.l.xs[(i0 >> 8) * 258 + (i0 & 255)] = a;
    *(uv4*)&sm.l.xs[(i1 >> 8) * 258 + (i1 & 255)] = b;
  }
  __syncthreads();
  const int g = tid & 31, ks = tid >> 5;
  const int rg = g >> 1, bg = g & 1;
  const int R0 = ((rg >> 2) << 9) + (cgI << 4) + ((rg & 3) << 2);
  const unsigned* wb = (const unsigned*)W16;
  const unsigned* wp0 = wb + (size_t)(R0 + 0) * 512 + ks * 32;
  const unsigned* wp1 = wb + (size_t)(R0 + 1) * 512 + ks * 32;
  const unsigned* wp2 = wb + (size_t)(R0 + 2) * 512 + ks * 32;
  const unsigned* wp3 = wb + (size_t)(R0 + 3) * 512 + ks * 32;
  const unsigned* xl = (const unsigned*)sm.l.xs;
  const int xbase = bg * 4 * 516 + ks * 32;
  float acc[4][4];
#pragma unroll
  for (int i = 0; i < 4; ++i)
#pragma unroll
    for (int j = 0; j < 4; ++j) acc[i][j] = 0.f;
#pragma unroll
  for (int kk = 0; kk < 8; ++kk) {
    uv4 wv[4], xv[4];
    wv[0] = *(const uv4*)&wp0[kk * 4];
    wv[1] = *(const uv4*)&wp1[kk * 4];
    wv[2] = *(const uv4*)&wp2[kk * 4];
    wv[3] = *(const uv4*)&wp3[kk * 4];
#pragma unroll
    for (int j = 0; j < 4; ++j)
      xv[j] = *(const uv4*)&xl[xbase + j * 516 + kk * 4];
#pragma unroll
    for (int i = 0; i < 4; ++i) {
#pragma unroll
      for (int j = 0; j < 4; ++j) {
        acc[i][j] = dot2acc(xv[j].x, wv[i].x, acc[i][j]);
        acc[i][j] = dot2acc(xv[j].y, wv[i].y, acc[i][j]);
        acc[i][j] = dot2acc(xv[j].z, wv[i].z, acc[i][j]);
        acc[i][j] = dot2acc(xv[j].w, wv[i].w, acc[i][j]);
      }
    }
  }
  __syncthreads();  // xs dead; red overlays
#pragma unroll
  for (int i = 0; i < 4; ++i)
#pragma unroll
    for (int j = 0; j < 4; ++j) acc[i][j] += __shfl_xor(acc[i][j], 32);
  if ((tid & 32) == 0) {
    const int wtid = (tid >> 6) * 32 + g;
#pragma unroll
    for (int i = 0; i < 4; ++i)
#pragma unroll
      for (int j = 0; j < 4; ++j)
        sm.l.r.red[wtid * 17 + i * 4 + j] = acc[i][j];
  }
  __syncthreads();
  {
    const int o = tid;
    const int org = o >> 5, oi = (o >> 3) & 3, obg = (o >> 2) & 1, oj = o & 3;
    const int gslot = org * 2 + obg, idx = oi * 4 + oj;
    float s = 0.f;
#pragma unroll
    for (int kp = 0; kp < 8; ++kp)
      s += sm.l.r.red[(kp * 32 + gslot) * 17 + idx];
    const int r = o >> 3, bl = o & 7;
    sm.l.r.gates[bl * 65 + r] = s;
  }
  __syncthreads();
  if (tid < 128) {
    const int bl = tid >> 4, uu = tid & 15;
    const int u = (cgI << 4) + uu;
    const float* gts = &sm.l.r.gates[bl * 65];
    const float gi = gts[uu] + bsum[u];
    const float gf = gts[16 + uu] + bsum[512 + u];
    const float gG = gts[32 + uu] + bsum[1024 + u];
    const float go = gts[48 + uu] + bsum[1536 + u];
    const float si = 1.f / (1.f + expf(-gi));
    const float sf = 1.f / (1.f + expf(-gf));
    const float so = 1.f / (1.f + expf(-go));
    const float cn = sf * creg + si * tanhf(gG);
    const float hn = so * tanhf(cn);
    creg = cn;
    sm.hl[bl][uu] = __half_as_ushort(__float2half(hn));
  }
  __syncthreads();
  if (tid < 16) {  // 16B h stores: bl = tid>>1, half = tid&1
    const int bl = tid >> 1, half = tid & 1;
    const uv4 v = *(const uv4*)&sm.hl[bl][half * 8];
    const size_t hbase = (size_t)(b0 + bl) * 1024 + (cgI << 4) + half * 8;
    cstore_u128(d1 + (hbase + o1) * 2, v);
    if (d2) cstore_u128(d2 + (hbase + o2) * 2, v);
  }
  __syncthreads();
}

// --------------------- attention (incl. its own q) ------------------------
__device__ __forceinline__ void attn_stage(
    SM& sm, int b, int t, const char* X3n, const unsigned short* Wq16,
    const float* __restrict__ bq, const __half* __restrict__ key16,
    const __half* __restrict__ val16, const float* __restrict__ amask,
    char* X1n, float* __restrict__ dout) {
  const int tid = threadIdx.x;
  if (tid < 64) {
    const uv4 v = cload_u128(X3n + ((size_t)b * 1024 + 512) * 2 + tid * 16);
    *(uv4*)&sm.a.h3u[tid * 4] = v;
  }
  __syncthreads();
  {  // q = h3 @ Wq.T
    const int c = tid & 255, kh = tid >> 8;
    const unsigned* wq = (const unsigned*)Wq16 + (size_t)c * 256 + kh * 128;
    const unsigned* hp = &sm.a.h3u[kh * 128];
    float a = 0.f;
#pragma unroll 8
    for (int i = 0; i < 32; ++i) {
      const uv4 w4 = *(const uv4*)&wq[i * 4];
      const uv4 x4 = *(const uv4*)&hp[i * 4];
      a = dot2acc(x4.x, w4.x, a);
      a = dot2acc(x4.y, w4.y, a);
      a = dot2acc(x4.z, w4.z, a);
      a = dot2acc(x4.w, w4.w, a);
    }
    sm.a.qp[kh][c] = a;
  }
  __syncthreads();
  if (tid < 256) sm.a.qf[tid] = sm.a.qp[0][tid] + sm.a.qp[1][tid] + bq[tid];
  __syncthreads();
  if (tid < 128) sm.a.qh[tid] = pack2h(sm.a.qf[2 * tid], sm.a.qf[2 * tid + 1]);
  __syncthreads();
  float e = -1e30f;
  if (tid < SS) {
    const unsigned* kp = (const unsigned*)key16 + ((size_t)b * SS + tid) * 128;
    float a = 0.f;
#pragma unroll 8
    for (int i = 0; i < 32; ++i) {
      const uv4 k4 = *(const uv4*)&kp[i * 4];
      const uv4 q4 = *(const uv4*)&sm.a.qh[i * 4];
      a = dot2acc(q4.x, k4.x, a);
      a = dot2acc(q4.y, k4.y, a);
      a = dot2acc(q4.z, k4.z, a);
      a = dot2acc(q4.w, k4.w, a);
    }
    e = a;
  }
  float m = e;
  for (int o = 32; o; o >>= 1) m = fmaxf(m, __shfl_xor(m, o));
  if ((tid & 63) == 0) sm.a.red[tid >> 6] = m;
  __syncthreads();
  m = sm.a.red[0];
#pragma unroll
  for (int i = 1; i < 8; ++i) m = fmaxf(m, sm.a.red[i]);
  __syncthreads();
  const float p = (tid < SS) ? expf(e - m) : 0.f;
  float z = p;
  for (int o = 32; o; o >>= 1) z += __shfl_xor(z, o);
  if ((tid & 63) == 0) sm.a.red[tid >> 6] = z;
  __syncthreads();
  z = 0.f;
#pragma unroll
  for (int i = 0; i < 8; ++i) z += sm.a.red[i];
  __syncthreads();
  const float at = p / z;
  if (b == 0 && tid < SS) dout[1 + (size_t)t * SS + tid] = at;
  const float am = (tid < SS) ? at * amask[(size_t)b * SS + tid] : 0.f;
  float sa = fabsf(am);
  for (int o = 32; o; o >>= 1) sa += __shfl_xor(sa, o);
  if ((tid & 63) == 0) sm.a.red[tid >> 6] = sa;
  __syncthreads();
  sa = 0.f;
#pragma unroll
  for (int i = 0; i < 8; ++i) sa += sm.a.red[i];
  const float inv = 1.f / fmaxf(sa, 1e-12f);
  if (tid < SS) sm.a.an[tid] = am * inv;
  __syncthreads();
  {  // ctx: 64 k-quads x 8 s-slices, 8B NT loads
    const int kq = tid & 63, sq = tid >> 6;
    const __half* vp = val16 + ((size_t)b * SS + sq * 50) * 256 + kq * 4;
    const float* ap = &sm.a.an[sq * 50];
    float a0 = 0.f, a1 = 0.f, a2 = 0.f, a3 = 0.f;
#pragma unroll 5
    for (int s = 0; s < 50; ++s) {
      const u64 u =
          __builtin_nontemporal_load((const u64*)(vp + (size_t)s * 256));
      const unsigned lo = (unsigned)u, hi = (unsigned)(u >> 32);
      const float2 f0 = __half22float2(*(const __half2*)&lo);
      const float2 f1 = __half22float2(*(const __half2*)&hi);
      const float w = ap[s];
      a0 = fmaf(w, f0.x, a0);
      a1 = fmaf(w, f0.y, a1);
      a2 = fmaf(w, f1.x, a2);
      a3 = fmaf(w, f1.y, a3);
    }
    float* cx = &sm.a.cxp[sq][kq * 4];
    cx[0] = a0;
    cx[1] = a1;
    cx[2] = a2;
    cx[3] = a3;
  }
  __syncthreads();
  if (tid < 128) {
    float v0 = 0.f, v1 = 0.f;
#pragma unroll
    for (int i = 0; i < 8; ++i) {
      v0 += sm.a.cxp[i][2 * tid];
      v1 += sm.a.cxp[i][2 * tid + 1];
    }
    const unsigned pk = pack2h(v0, v1);
    const unsigned p1 = __shfl_down(pk, 1);
    const unsigned p2 = __shfl_down(pk, 2);
    const unsigned p3 = __shfl_down(pk, 3);
    if ((tid & 3) == 0) {
      uv4 v;
      v.x = pk;
      v.y = p1;
      v.z = p2;
      v.w = p3;
      cstore_u128(X1n + ((size_t)b * 1024 + 256 + 2 * tid) * 2, v);
    }
  }
  __syncthreads();
}

// ------------------------------ logits + nll ------------------------------
__device__ __forceinline__ void logits_stage(SM& sm, int b, int t,
                                             const char* X3n,
                                             const float* __restrict__ WvT,
                                             const float* __restrict__ bv,
                                             const int* __restrict__ target,
                                             const float* __restrict__ tmask,
                                             float& lreg) {
  const int tid = threadIdx.x;
  if (tid < 64) {
    const uv4 v = cload_u128(X3n + ((size_t)b * 1024 + 512) * 2 + tid * 16);
    const unsigned uu[4] = {v.x, v.y, v.z, v.w};
#pragma unroll
    for (int j = 0; j < 4; ++j) {
      const float2 f = __half22float2(*(const __half2*)&uu[j]);
      sm.g.h3f[tid * 8 + 2 * j] = f.x;
      sm.g.h3f[tid * 8 + 2 * j + 1] = f.y;
    }
  }
  __syncthreads();
  {
    const int c = tid & 63, ks = tid >> 6;
    if (c < VV) {
      float a = 0.f;
      const float* hp = &sm.g.h3f[ks * 64];
      const float* wp = WvT + (size_t)(ks * 64) * VV + c;
#pragma unroll 4
      for (int h = 0; h < 64; ++h) a = fmaf(hp[h], wp[h * VV], a);
      sm.g.redl[c * 8 + ks] = a;
    }
  }
  __syncthreads();
  if (tid < VV) {
    const float* rp = &sm.g.redl[tid * 8];
    float l = bv[tid];
#pragma unroll
    for (int k = 0; k < 8; ++k) l += rp[k];
    sm.g.lbuf[tid] = l;
  }
  __syncthreads();
  if (tid == 0) {
    float M = sm.g.lbuf[0];
    for (int v = 1; v < VV; ++v) M = fmaxf(M, sm.g.lbuf[v]);
    float Z = 0.f;
    for (int v = 0; v < VV; ++v) Z += expf(sm.g.lbuf[v] - M);
    const int yy = target[t * BB + b];
    lreg += tmask[t * BB + b] * (-(sm.g.lbuf[yy] - M - logf(Z)));
  }
  __syncthreads();
}

// --------------------------------- main -----------------------------------
__global__ void __launch_bounds__(TPB, 1) kmain(
    const int* __restrict__ target, const float* __restrict__ tmask,
    const float* __restrict__ amask, const float* __restrict__ emb,
    const float* __restrict__ bq, const float* __restrict__ bv,
    const float* __restrict__ cx1, const float* __restrict__ cx2,
    const float* __restrict__ cx3, char* wsb, float* __restrict__ dout) {
  __shared__ SM sm;
  __shared__ int s_wid;
  const int wg = blockIdx.x, tid = threadIdx.x;
  unsigned* bar = (unsigned*)(wsb + OBAR);
  unsigned* flags = bar;
  unsigned* epoch = bar + 260;
  const unsigned short* W1 = (const unsigned short*)(wsb + OW16);
  const unsigned short* W2 = W1 + 2097152;
  const unsigned short* W3 = W2 + 2097152;
  const unsigned short* Wq16 = (const unsigned short*)(wsb + OWQ);
  const __half* key16 = (const __half*)(wsb + OKEY);
  const __half* val16 = (const __half*)(wsb + OVAL);
  const float* bs1 = (const float*)(wsb + OBS1);
  const float* bs2 = (const float*)(wsb + OBS2);
  const float* bs3 = (const float*)(wsb + OBS3);
  const float* WvT = (const float*)(wsb + OWVT);
  float* lacc = (float*)(wsb + OLACC);

  // ---- XCD-affine workid claim ----
  if (tid == 0) {
    unsigned xcc = 0;
    asm volatile("s_getreg_b32 %0, hwreg(20, 0, 32)" : "=s"(xcc));
    xcc &= 7u;
    unsigned* cnt = bar + 288;
    unsigned* claim = bar + 320;
    int wid = -1;
    const unsigned r = __hip_atomic_fetch_add(&cnt[xcc], 1u, __ATOMIC_RELAXED,
                                              __HIP_MEMORY_SCOPE_AGENT);
    if (r < 32u) {
      const int cand = (int)(xcc * 32u + r);
      if (__hip_atomic_exchange(&claim[cand], 1u, __ATOMIC_RELAXED,
                                __HIP_MEMORY_SCOPE_AGENT) == 0u)
        wid = cand;
    }
    for (int i = 0; wid < 0 && i < 256; ++i)
      if (__hip_atomic_exchange(&claim[i], 1u, __ATOMIC_RELAXED,
                                __HIP_MEMORY_SCOPE_AGENT) == 0u)
        wid = i;
    s_wid = wid;
  }
  __syncthreads();
  const int Wd = s_wid;
  const int xcls = Wd >> 5, lw = Wd & 31;
  const int cgI = xcls * 4 + (lw & 3);
  const int b0 = ((lw >> 2) & 7) * 8;

  float c1r = 0.f, c2r = 0.f, c3r = 0.f;
  if (tid < 128) {
    const int u = (cgI << 4) + (tid & 15);
    c1r = cx1[u];
    c2r = cx2[u];
    c3r = cx3[u];
  }
  float lreg = 0.f;
  unsigned bst = 1;

  for (int t = 0; t < NSTEP; ++t) {
    const int cur = t & 1, nxt = cur ^ 1;
    char* X1c = wsb + OX1 + (size_t)cur * 131072;
    char* X1n = wsb + OX1 + (size_t)nxt * 131072;
    char* X2c = wsb + OX2 + (size_t)cur * 131072;
    char* X2n = wsb + OX2 + (size_t)nxt * 131072;
    char* X3c = wsb + OX3 + (size_t)cur * 131072;
    char* X3n = wsb + OX3 + (size_t)nxt * 131072;

    lstm_stage(sm, cgI, b0, X1c, W1, bs1, c1r, X2c, 0, X1n, 512);
    gbar(flags, epoch, wg, bst++);
    lstm_stage(sm, cgI, b0, X2c, W2, bs2, c2r, X3c, 0, X2n, 512);
    gbar(flags, epoch, wg, bst++);
    lstm_stage(sm, cgI, b0, X3c, W3, bs3, c3r, X3n, 512, nullptr, 0);
    gbar(flags, epoch, wg, bst++);
    if (lw < 8) {
      attn_stage(sm, xcls * 8 + lw, t, X3n, Wq16, bq, key16, val16, amask,
                 X1n, dout);
    } else if (lw < 16) {
      if (t < TT)
        logits_stage(sm, xcls * 8 + lw - 8, t, X3n, WvT, bv, target, tmask,
                     lreg);
    } else if (lw < 24) {
      const int b = xcls * 8 + lw - 16;
      if (t < TT && tid < 32) {
        const int y = target[t * BB + b];
        const float4 f0 = *(const float4*)&emb[(size_t)y * EE + tid * 8];
        const float4 f1 = *(const float4*)&emb[(size_t)y * EE + tid * 8 + 4];
        const u64 lo = pack4h(f0), hi = pack4h(f1);
        uv4 v;
        v.x = (unsigned)lo;
        v.y = (unsigned)(lo >> 32);
        v.z = (unsigned)hi;
        v.w = (unsigned)(hi >> 32);
        cstore_u128(X1n + ((size_t)b * 1024 + tid * 8) * 2, v);
      }
    }
    gbar(flags, epoch, wg, bst++);
  }
  if (lw >= 8 && lw < 16 && tid == 0)
    astore_u32((unsigned*)&lacc[xcls * 8 + lw - 8], __float_as_uint(lreg));
  gbar(flags, epoch, wg, bst++);
  if (Wd == 0 && tid < 64) {
    float v = __uint_as_float(aload_u32((const unsigned*)&lacc[tid]));
    for (int o = 32; o; o >>= 1) v += __shfl_xor(v, o);
    if (tid == 0) dout[0] = v * (1.f / 64.f);
  }
}

// ---------------------------------- init ----------------------------------
__global__ void k_init(const float* emb, const float* Wq, const float* bq,
                       const float* Wv, const float* bih1, const float* bhh1,
                       const float* bih2, const float* bhh2, const float* bih3,
                       const float* bhh3, const float* hx1, const float* hx2,
                       const float* hx3, char* wsb) {
  const int b = blockIdx.x, tid = threadIdx.x;
  __half* X1 = (__half*)(wsb + OX1);
  __half* X2 = (__half*)(wsb + OX2);
  __half* X3 = (__half*)(wsb + OX3);
  __shared__ float hx[HH];
  for (int k = tid; k < HH; k += 256) {
    const float v = hx1[k];
    hx[k] = v;
    X1[b * 1024 + 512 + k] = __float2half(v);
    X2[b * 1024 + 512 + k] = __float2half(hx2[k]);
    X3[b * 1024 + 512 + k] = __float2half(hx3[k]);
  }
  for (int k = tid; k < EE; k += 256) X1[b * 1024 + k] = __float2half(emb[k]);
  __syncthreads();
  for (int c = tid; c < KD; c += 256) {
    float a = bq[c];
    for (int k = 0; k < HH; ++k) a = fmaf(hx[k], Wq[(size_t)c * HH + k], a);
    X1[b * 1024 + 256 + c] = __float2half(a);
  }
  if (b == 0) {
    float* s1 = (float*)(wsb + OBS1);
    float* s2 = (float*)(wsb + OBS2);
    float* s3 = (float*)(wsb + OBS3);
    for (int i = tid; i < 2048; i += 256) {
      s1[i] = bih1[i] + bhh1[i];
      s2[i] = bih2[i] + bhh2[i];
      s3[i] = bih3[i] + bhh3[i];
    }
    float* wvt = (float*)(wsb + OWVT);
    for (int i = tid; i < HH * VV; i += 256) {
      const int h = i / VV, v = i % VV;
      wvt[i] = Wv[(size_t)v * HH + h];
    }
    float* lacc = (float*)(wsb + OLACC);
    for (int i = tid; i < 64; i += 256) lacc[i] = 0.f;
    unsigned* bar = (unsigned*)(wsb + OBAR);
    for (int i = tid; i < 1024; i += 256) bar[i] = 0u;
  }
}

// ----------------------------- fp16 staging -------------------------------
__global__ void k_cvt(const float* key, const float* val, const float* Wq,
                      const float* Wih1, const float* Whh1, const float* Wih2,
                      const float* Whh2, const float* Wih3, const float* Whh3,
                      char* wsb) {
  const int blk = blockIdx.x, tid = threadIdx.x;
  if (blk < 6144) {
    const int layer = blk >> 11, R = blk & 2047;
    const float* Wih = (layer == 0) ? Wih1 : ((layer == 1) ? Wih2 : Wih3);
    const float* Whh = (layer == 0) ? Whh1 : ((layer == 1) ? Whh2 : Whh3);
    __half* dst = (__half*)(wsb + OW16) + (size_t)layer * 2097152 +
                  (size_t)R * 1024;
    const int k0 = tid * 4;
    const float* src = (k0 < 512) ? &Wih[(size_t)R * 512 + k0]
                                  : &Whh[(size_t)R * 512 + (k0 - 512)];
    const float4 v = *(const float4*)src;
    dst[k0 + 0] = __float2half(v.x);
    dst[k0 + 1] = __float2half(v.y);
    dst[k0 + 2] = __float2half(v.z);
    dst[k0 + 3] = __float2half(v.w);
  } else if (blk < 7744) {
    const size_t base = (size_t)(blk - 6144) * 4096 + (size_t)tid * 16;
    __half* dst = (__half*)(wsb + OKEY);
#pragma unroll
    for (int j = 0; j < 4; ++j) {
      const float4 v = *(const float4*)&key[base + j * 4];
      dst[base + j * 4 + 0] = __float2half(v.x);
      dst[base + j * 4 + 1] = __float2half(v.y);
      dst[base + j * 4 + 2] = __float2half(v.z);
      dst[base + j * 4 + 3] = __float2half(v.w);
    }
  } else if (blk < 9344) {
    const size_t base = (size_t)(blk - 7744) * 4096 + (size_t)tid * 16;
    __half* dst = (__half*)(wsb + OVAL);
#pragma unroll
    for (int j = 0; j < 4; ++j) {
      const float4 v = *(const float4*)&val[base + j * 4];
      dst[base + j * 4 + 0] = __float2half(v.x);
      dst[base + j * 4 + 1] = __float2half(v.y);
      dst[base + j * 4 + 2] = __float2half(v.z);
      dst[base + j * 4 + 3] = __float2half(v.w);
    }
  } else {
    const size_t base = (size_t)(blk - 9344) * 4096 + (size_t)tid * 16;
    __half* dst = (__half*)(wsb + OWQ);
#pragma unroll
    for (int j = 0; j < 4; ++j) {
      const float4 v = *(const float4*)&Wq[base + j * 4];
      dst[base + j * 4 + 0] = __float2half(v.x);
      dst[base + j * 4 + 1] = __float2half(v.y);
      dst[base + j * 4 + 2] = __float2half(v.z);
      dst[base + j * 4 + 3] = __float2half(v.w);
    }
  }
}

// --------------------------------- launch ---------------------------------
extern "C" void kernel_launch(void* const* d_in, const int* in_sizes, int n_in,
                              void* d_out, int out_size, void* d_ws,
                              size_t ws_size, hipStream_t stream) {
  const int* target = (const int*)d_in[0];
  const float* tmask = (const float*)d_in[1];
  const float* key = (const float*)d_in[2];
  const float* val = (const float*)d_in[3];
  const float* amask = (const float*)d_in[4];
  const float* emb = (const float*)d_in[5];
  const float* Wih1 = (const float*)d_in[6];
  const float* Whh1 = (const float*)d_in[7];
  const float* bih1 = (const float*)d_in[8];
  const float* bhh1 = (const float*)d_in[9];
  const float* Wih2 = (const float*)d_in[10];
  const float* Whh2 = (const float*)d_in[11];
  const float* bih2 = (const float*)d_in[12];
  const float* bhh2 = (const float*)d_in[13];
  const float* Wih3 = (const float*)d_in[14];
  const float* Whh3 = (const float*)d_in[15];
  const float* bih3 = (const float*)d_in[16];
  const float* bhh3 = (const float*)d_in[17];
  const float* Wq = (const float*)d_in[18];
  const float* bq = (const float*)d_in[19];
  const float* Wv = (const float*)d_in[20];
  const float* bv = (const float*)d_in[21];
  const float* hx1 = (const float*)d_in[22];
  const float* cx1 = (const float*)d_in[23];
  const float* hx2 = (const float*)d_in[24];
  const float* cx2 = (const float*)d_in[25];
  const float* hx3 = (const float*)d_in[26];
  const float* cx3 = (const float*)d_in[27];
  float* out = (float*)d_out;
  char* wsb = (char*)d_ws;

  hipLaunchKernelGGL(k_init, dim3(64), dim3(256), 0, stream, emb, Wq, bq, Wv,
                     bih1, bhh1, bih2, bhh2, bih3, bhh3, hx1, hx2, hx3, wsb);
  hipLaunchKernelGGL(k_cvt, dim3(9376), dim3(256), 0, stream, key, val, Wq,
                     Wih1, Whh1, Wih2, Whh2, Wih3, Whh3, wsb);

  void* args[] = {(void*)&target, (void*)&tmask, (void*)&amask, (void*)&emb,
                  (void*)&bq,     (void*)&bv,    (void*)&cx1,   (void*)&cx2,
                  (void*)&cx3,    (void*)&wsb,   (void*)&out};
  hipLaunchCooperativeKernel((const void*)kmain, dim3(NWG), dim3(TPB), args, 0,
                             stream);
}